// Round 13
// baseline (177.434 us; speedup 1.0000x reference)
//
#include <hip/hip_runtime.h>

#define DD 128   // embed dim
#define HH 256   // hidden dim
#define K1 256   // 2*DD
#define BM 64    // node tile
#define CH 2048  // edges per chunk in legacy bucket scatter
#define CHP 8192 // edges per chunk in LDS-staged part_k
#define CAP 8192 // max edges per bucket for LDS-staged sort

typedef __bf16 bf16;
typedef __attribute__((ext_vector_type(8))) __bf16 bf16x8;
typedef __attribute__((ext_vector_type(4))) float f32x4;
typedef __attribute__((ext_vector_type(2))) float f32x2;

// ============================================================================
// graph sort: bucket (B=2^BSH<=256 dsts, NB<=512 buckets) 2-pass sort with
// int-packed (dloc<<24|src) pairs. Produces ssrc + offs (inclusive ends).
// ============================================================================

__global__ __launch_bounds__(256) void countb_k(const int* __restrict__ dst,
                                                int* __restrict__ bcnt,
                                                int E, int BSH) {
    __shared__ int c[512];
    for (int j = threadIdx.x; j < 512; j += 256) c[j] = 0;
    __syncthreads();
    for (int e = blockIdx.x * 256 + threadIdx.x; e < E; e += gridDim.x * 256)
        atomicAdd(&c[dst[e] >> BSH], 1);
    __syncthreads();
    for (int j = threadIdx.x; j < 512; j += 256)
        if (c[j]) atomicAdd(&bcnt[j], c[j]);
}

__global__ __launch_bounds__(512) void scanb_k(const int* __restrict__ bcnt,
                                               int* __restrict__ bbase,
                                               int* __restrict__ bpos,
                                               int NB, int E) {
    __shared__ int s[512];
    const int t = threadIdx.x;
    int v = (t < NB) ? bcnt[t] : 0;
    s[t] = v;
    __syncthreads();
    for (int off = 1; off < 512; off <<= 1) {
        int y = (t >= off) ? s[t - off] : 0;
        __syncthreads();
        s[t] += y;
        __syncthreads();
    }
    int excl = s[t] - v;
    if (t < NB) { bbase[t] = excl; bpos[t] = excl; }
    if (t == 0) bbase[NB] = E;
}

// pass 1: LDS-staged partition into bucket-contiguous runs of packed pairs.
// Per 8192-edge chunk: count -> LDS scan -> reserve global runs -> scatter
// into 32KB LDS stage -> contiguous per-run write-out (waves own buckets).
__global__ __launch_bounds__(256) void part_k(const int* __restrict__ src,
                                              const int* __restrict__ dst,
                                              int* __restrict__ bpos,
                                              unsigned* __restrict__ pairs,
                                              int E, int BSH, int Bm1) {
    __shared__ int lcnt[512];
    __shared__ int lpref[512];
    __shared__ int lrun[512];
    __shared__ int gbase[512];
    __shared__ unsigned stage[CHP];  // 32 KB
    const int t = threadIdx.x;
    const int e0 = blockIdx.x * CHP;
    const int e1 = min(E, e0 + CHP);
    for (int j = t; j < 512; j += 256) lcnt[j] = 0;
    __syncthreads();
    for (int e = e0 + t; e < e1; e += 256)
        atomicAdd(&lcnt[dst[e] >> BSH], 1);
    __syncthreads();
    for (int j = t; j < 512; j += 256) lpref[j] = lcnt[j];
    __syncthreads();
    for (int off = 1; off < 512; off <<= 1) {
        int j2 = t + 256;
        int v0 = (t >= off) ? lpref[t - off] : 0;
        int v1 = (j2 >= off) ? lpref[j2 - off] : 0;
        __syncthreads();
        lpref[t] += v0;
        lpref[j2] += v1;
        __syncthreads();
    }
    for (int j = t; j < 512; j += 256) {
        int c = lcnt[j];
        gbase[j] = c ? atomicAdd(&bpos[j], c) : 0;
        lrun[j] = lpref[j] - c;   // exclusive prefix
    }
    __syncthreads();
    for (int e = e0 + t; e < e1; e += 256) {
        int d = dst[e];
        int b = d >> BSH;
        int pos = atomicAdd(&lrun[b], 1);
        stage[pos] = ((unsigned)(d & Bm1) << 24) | (unsigned)src[e];
    }
    __syncthreads();
    const int wv = t >> 6, ln = t & 63;
    for (int b = wv; b < 512; b += 4) {
        int s = lpref[b] - lcnt[b];
        int c = lcnt[b];
        int g = gbase[b];
        for (int i = ln; i < c; i += 64)
            pairs[g + i] = stage[s + i];
    }
}

// pass 2: one block per bucket — per-dst LDS histogram+scan (writes offs),
// LDS-staged counting sort, dense coalesced ssrc write-out.
__global__ __launch_bounds__(256) void sortb_k(const unsigned* __restrict__ pairs,
                                               const int* __restrict__ bbase,
                                               int* __restrict__ offs,
                                               int* __restrict__ ssrc,
                                               int N, int BSH) {
    __shared__ int hist[512];
    __shared__ int pref[512];
    __shared__ int run[512];
    __shared__ int sorted[CAP];
    const int t = threadIdx.x;
    const int b = blockIdx.x;
    const int B = 1 << BSH;
    const int d0 = b << BSH;
    const int nd = min(B, N - d0);
    const int rb = bbase[b], re = bbase[b + 1];
    const int cntE = re - rb;
    for (int j = t; j < 512; j += 256) hist[j] = 0;
    __syncthreads();
    for (int i = rb + t; i < re; i += 256)
        atomicAdd(&hist[pairs[i] >> 24], 1);
    __syncthreads();
    for (int j = t; j < 512; j += 256) pref[j] = hist[j];
    __syncthreads();
    for (int off = 1; off < 512; off <<= 1) {
        int j2 = t + 256;
        int v0 = (t >= off) ? pref[t - off] : 0;
        int v1 = (j2 >= off) ? pref[j2 - off] : 0;
        __syncthreads();
        pref[t] += v0;
        pref[j2] += v1;
        __syncthreads();
    }
    for (int j = t; j < nd; j += 256) offs[d0 + j] = rb + pref[j];
    for (int j = t; j < 512; j += 256) run[j] = pref[j] - hist[j];
    __syncthreads();
    if (cntE <= CAP) {
        for (int i = rb + t; i < re; i += 256) {
            unsigned p = pairs[i];
            int pos = atomicAdd(&run[p >> 24], 1);
            sorted[pos] = (int)(p & 0xFFFFFFu);
        }
        __syncthreads();
        for (int i = t; i < cntE; i += 256) ssrc[rb + i] = sorted[i];
    } else {
        for (int i = rb + t; i < re; i += 256) {
            unsigned p = pairs[i];
            int pos = atomicAdd(&run[p >> 24], 1);
            ssrc[rb + pos] = (int)(p & 0xFFFFFFu);
        }
    }
}

// ============================================================================
// legacy graph kernels (fallback when ws too small / shapes odd)
// ============================================================================

__global__ __launch_bounds__(256) void hist_k(const int* __restrict__ dst,
                                              int* __restrict__ cnt, int E) {
    for (int e = blockIdx.x * blockDim.x + threadIdx.x; e < E;
         e += gridDim.x * blockDim.x)
        atomicAdd(&cnt[dst[e]], 1);
}

__global__ __launch_bounds__(256) void scan1_k(const int* __restrict__ cnt,
                                               int* __restrict__ offs,
                                               int* __restrict__ part, int N) {
    __shared__ int sdata[256];
    const int b = blockIdx.x, t = threadIdx.x;
    const int base = b * 1024 + t * 4;
    int v[4], sum = 0;
    #pragma unroll
    for (int i = 0; i < 4; ++i) {
        int idx = base + i;
        v[i] = (idx < N) ? cnt[idx] : 0;
        sum += v[i];
    }
    sdata[t] = sum;
    __syncthreads();
    for (int off = 1; off < 256; off <<= 1) {
        int y = (t >= off) ? sdata[t - off] : 0;
        __syncthreads();
        sdata[t] += y;
        __syncthreads();
    }
    int excl = sdata[t] - sum;
    if (t == 255) part[b] = sdata[255];
    int run = excl;
    #pragma unroll
    for (int i = 0; i < 4; ++i) {
        int idx = base + i;
        if (idx < N) offs[idx] = run;
        run += v[i];
    }
}

__global__ __launch_bounds__(128) void scan2_k(int* __restrict__ part, int nparts) {
    __shared__ int sdata[128];
    const int t = threadIdx.x;
    int v = (t < nparts) ? part[t] : 0;
    sdata[t] = v;
    __syncthreads();
    for (int off = 1; off < 128; off <<= 1) {
        int y = (t >= off) ? sdata[t - off] : 0;
        __syncthreads();
        sdata[t] += y;
        __syncthreads();
    }
    if (t < nparts) part[t] = sdata[t] - v;
}

__global__ __launch_bounds__(256) void scan3_k(int* __restrict__ offs,
                                               const int* __restrict__ part, int N) {
    for (int i = blockIdx.x * blockDim.x + threadIdx.x; i < N;
         i += gridDim.x * blockDim.x)
        offs[i] += part[i >> 10];
}

__global__ __launch_bounds__(256) void bucket_k(const int* __restrict__ src,
                                                const int* __restrict__ dst,
                                                int* __restrict__ offs,
                                                int* __restrict__ ssrc,
                                                int E, int N) {
    const int r = blockIdx.x & 7;
    const int chunk = blockIdx.x >> 3;
    const int lo = r * (N >> 3);
    const int hi = (r == 7) ? N : lo + (N >> 3);
    const int e0 = chunk * CH;
    const int e1 = min(E, e0 + CH);
    for (int e = e0 + threadIdx.x; e < e1; e += 256) {
        int d = dst[e];
        if (d >= lo && d < hi) {
            int pos = atomicAdd(&offs[d], 1);
            ssrc[pos] = src[e];
        }
    }
}

// fp32-row gather (legacy fallback); writes fp32 nbr
__global__ __launch_bounds__(256) void gather_k(const float* __restrict__ emb,
                                                const int* __restrict__ offs,
                                                const int* __restrict__ ssrc,
                                                float* __restrict__ nbr, int N) {
    const int wid = threadIdx.x >> 6;
    const int lane = threadIdx.x & 63;
    const int d = blockIdx.x * 4 + wid;
    if (d >= N) return;
    const int sub = lane >> 5;
    const int c = (lane & 31) * 4;
    const int start = (d == 0) ? 0 : offs[d - 1];
    const int end = offs[d];
    float4 acc = make_float4(0.f, 0.f, 0.f, 0.f);
    int e = start;
    for (; e + 4 <= end; e += 4) {
        int s0 = ssrc[e + sub];
        int s1 = ssrc[e + 2 + sub];
        float4 v0 = *reinterpret_cast<const float4*>(&emb[(size_t)s0 * DD + c]);
        float4 v1 = *reinterpret_cast<const float4*>(&emb[(size_t)s1 * DD + c]);
        acc.x += v0.x + v1.x; acc.y += v0.y + v1.y;
        acc.z += v0.z + v1.z; acc.w += v0.w + v1.w;
    }
    for (; e + 2 <= end; e += 2) {
        int s = ssrc[e + sub];
        float4 v = *reinterpret_cast<const float4*>(&emb[(size_t)s * DD + c]);
        acc.x += v.x; acc.y += v.y; acc.z += v.z; acc.w += v.w;
    }
    if (e < end && sub == 0) {
        int s = ssrc[e];
        float4 v = *reinterpret_cast<const float4*>(&emb[(size_t)s * DD + c]);
        acc.x += v.x; acc.y += v.y; acc.z += v.z; acc.w += v.w;
    }
    acc.x += __shfl_xor(acc.x, 32);
    acc.y += __shfl_xor(acc.y, 32);
    acc.z += __shfl_xor(acc.z, 32);
    acc.w += __shfl_xor(acc.w, 32);
    if (sub == 0) {
        if (end > start) {
            float inv = 1.f / (float)(end - start);
            acc.x *= inv; acc.y *= inv; acc.z *= inv; acc.w *= inv;
        } else {
            acc = *reinterpret_cast<const float4*>(&emb[(size_t)d * DD + c]);
        }
        *reinterpret_cast<float4*>(&nbr[(size_t)d * DD + c]) = acc;
    }
}

// ============================================================================
// emb fp32 -> fp8 e4m3 copy (gather source; one 128B line per row)
// ============================================================================
__global__ __launch_bounds__(256) void cvt8_k(const float* __restrict__ emb,
                                              unsigned* __restrict__ emb8,
                                              size_t n8) {
    for (size_t i = blockIdx.x * blockDim.x + threadIdx.x; i < n8;
         i += (size_t)gridDim.x * blockDim.x) {
        float4 a = *reinterpret_cast<const float4*>(&emb[i * 8]);
        float4 b = *reinterpret_cast<const float4*>(&emb[i * 8 + 4]);
        int w0 = __builtin_amdgcn_cvt_pk_fp8_f32(a.x, a.y, 0, false);
        w0 = __builtin_amdgcn_cvt_pk_fp8_f32(a.z, a.w, w0, true);
        int w1 = __builtin_amdgcn_cvt_pk_fp8_f32(b.x, b.y, 0, false);
        w1 = __builtin_amdgcn_cvt_pk_fp8_f32(b.z, b.w, w1, true);
        uint2 o; o.x = (unsigned)w0; o.y = (unsigned)w1;
        *reinterpret_cast<uint2*>(&emb8[i * 2]) = o;
    }
}

// accumulate 8 fp8 (uint2) into acc[8]
__device__ __forceinline__ void acc8(float* acc, uint2 v) {
    f32x2 p;
    p = __builtin_amdgcn_cvt_pk_f32_fp8(v.x, false); acc[0] += p[0]; acc[1] += p[1];
    p = __builtin_amdgcn_cvt_pk_f32_fp8(v.x, true);  acc[2] += p[0]; acc[3] += p[1];
    p = __builtin_amdgcn_cvt_pk_f32_fp8(v.y, false); acc[4] += p[0]; acc[5] += p[1];
    p = __builtin_amdgcn_cvt_pk_f32_fp8(v.y, true);  acc[6] += p[0]; acc[7] += p[1];
}

// ============================================================================
// one wave per dst, fp8 rows (128B): 4 edge slots x 16 lanes x 8B, 4 loads in
// flight; HW fp8->f32 cvt; fp32 accumulate; bf16 out row.
// ============================================================================
__global__ __launch_bounds__(256) void gather8_k(const unsigned* __restrict__ emb8,
                                                 const float* __restrict__ emb,
                                                 const int* __restrict__ offs,
                                                 const int* __restrict__ ssrc,
                                                 bf16* __restrict__ nbrh, int N) {
    const int wid = threadIdx.x >> 6;
    const int lane = threadIdx.x & 63;
    const int d = blockIdx.x * 4 + wid;
    if (d >= N) return;
    const int slot = lane >> 4;          // 4 edge slots
    const int c8 = (lane & 15) * 8;      // fp8 column base (0..120)
    const int start = (d == 0) ? 0 : offs[d - 1];
    const int end = offs[d];
    float acc[8];
    #pragma unroll
    for (int j = 0; j < 8; ++j) acc[j] = 0.f;
    int e = start;
    for (; e + 16 <= end; e += 16) {
        int s0 = ssrc[e + slot];
        int s1 = ssrc[e + 4 + slot];
        int s2 = ssrc[e + 8 + slot];
        int s3 = ssrc[e + 12 + slot];
        uint2 v0 = *reinterpret_cast<const uint2*>(&emb8[((size_t)s0 * DD + c8) >> 2]);
        uint2 v1 = *reinterpret_cast<const uint2*>(&emb8[((size_t)s1 * DD + c8) >> 2]);
        uint2 v2 = *reinterpret_cast<const uint2*>(&emb8[((size_t)s2 * DD + c8) >> 2]);
        uint2 v3 = *reinterpret_cast<const uint2*>(&emb8[((size_t)s3 * DD + c8) >> 2]);
        acc8(acc, v0); acc8(acc, v1); acc8(acc, v2); acc8(acc, v3);
    }
    for (; e + 8 <= end; e += 8) {
        int s0 = ssrc[e + slot];
        int s1 = ssrc[e + 4 + slot];
        uint2 v0 = *reinterpret_cast<const uint2*>(&emb8[((size_t)s0 * DD + c8) >> 2]);
        uint2 v1 = *reinterpret_cast<const uint2*>(&emb8[((size_t)s1 * DD + c8) >> 2]);
        acc8(acc, v0); acc8(acc, v1);
    }
    for (; e + 4 <= end; e += 4) {
        int s0 = ssrc[e + slot];
        uint2 v0 = *reinterpret_cast<const uint2*>(&emb8[((size_t)s0 * DD + c8) >> 2]);
        acc8(acc, v0);
    }
    if (slot < end - e) {
        int s0 = ssrc[e + slot];
        uint2 v0 = *reinterpret_cast<const uint2*>(&emb8[((size_t)s0 * DD + c8) >> 2]);
        acc8(acc, v0);
    }
    #pragma unroll
    for (int j = 0; j < 8; ++j) {
        acc[j] += __shfl_xor(acc[j], 16);
        acc[j] += __shfl_xor(acc[j], 32);
    }
    if (slot == 0) {
        bf16x8 o;
        if (end > start) {
            float inv = 1.f / (float)(end - start);
            #pragma unroll
            for (int j = 0; j < 8; ++j) o[j] = (bf16)(acc[j] * inv);
        } else {
            float4 a = *reinterpret_cast<const float4*>(&emb[(size_t)d * DD + c8]);
            float4 b = *reinterpret_cast<const float4*>(&emb[(size_t)d * DD + c8 + 4]);
            o[0]=(bf16)a.x; o[1]=(bf16)a.y; o[2]=(bf16)a.z; o[3]=(bf16)a.w;
            o[4]=(bf16)b.x; o[5]=(bf16)b.y; o[6]=(bf16)b.z; o[7]=(bf16)b.w;
        }
        *reinterpret_cast<bf16x8*>(&nbrh[(size_t)d * DD + c8]) = o;
    }
}

// ============================================================================
// W pre-pack (both weights): fp32 [K x NC] -> bf16 B-fragments.
// ============================================================================
__global__ __launch_bounds__(64) void packW_k(const float* __restrict__ W1,
                                              const float* __restrict__ W2,
                                              bf16* __restrict__ w1h,
                                              bf16* __restrict__ w2h) {
    const int bid = blockIdx.x;
    const float* W; bf16* outp; int NC; int rel;
    if (bid < 128) { W = W1; outp = w1h; NC = HH; rel = bid; }
    else           { W = W2; outp = w2h; NC = DD; rel = bid - 128; }
    const int ntiles = NC >> 4;
    const int kt = rel / ntiles;
    const int nt = rel % ntiles;
    const int l = threadIdx.x;
    const int k0 = kt * 32 + (l >> 4) * 8;
    const int n = nt * 16 + (l & 15);
    bf16x8 hv;
    #pragma unroll
    for (int r = 0; r < 8; ++r)
        hv[r] = (bf16)W[(size_t)(k0 + r) * NC + n];
    *reinterpret_cast<bf16x8*>(outp + ((size_t)rel * 64 + l) * 8) = hv;
}

// ============================================================================
// MFMA MLP, 512 threads (8 waves), single bf16 plane (32 KB LDS).
// ============================================================================
__global__ __launch_bounds__(512) void mlp_mfma_k(const float* __restrict__ emb,
        const float* nbrf, const bf16* __restrict__ nbrh,
        const bf16* __restrict__ w1h, const float* __restrict__ b1,
        const bf16* __restrict__ w2h, const float* __restrict__ b2,
        float* out, int N) {
    __shared__ char smem[BM * K1 * 2];  // 32 KB: [64 rows][256 cols] bf16
    const int t = threadIdx.x;
    const int n0 = blockIdx.x * BM;
    const int l = t & 63;
    const int w = t >> 6;

    // ---- stage X (swizzled: byte_in_row ^= (row&7)<<4) ----
    #pragma unroll
    for (int i = 0; i < 4; ++i) {
        int chunk = i * 512 + t;          // 2048 chunks: 64 rows x 32
        int row = chunk >> 5;
        int c0 = (chunk & 31) * 8;
        int n = n0 + row;
        bf16x8 hv;
        if (n < N) {
            if (c0 >= DD && nbrh != nullptr) {
                hv = *reinterpret_cast<const bf16x8*>(&nbrh[(size_t)n * DD + (c0 - DD)]);
            } else {
                const float* sp = (c0 < DD) ? &emb[(size_t)n * DD + c0]
                                            : &nbrf[(size_t)n * DD + (c0 - DD)];
                float4 a = *reinterpret_cast<const float4*>(sp);
                float4 b = *reinterpret_cast<const float4*>(sp + 4);
                hv[0]=(bf16)a.x; hv[1]=(bf16)a.y; hv[2]=(bf16)a.z; hv[3]=(bf16)a.w;
                hv[4]=(bf16)b.x; hv[5]=(bf16)b.y; hv[6]=(bf16)b.z; hv[7]=(bf16)b.w;
            }
        } else {
            #pragma unroll
            for (int j = 0; j < 8; ++j) hv[j] = (bf16)0.f;
        }
        int off = row * 512 + ((c0 * 2) ^ ((row & 7) << 4));
        *reinterpret_cast<bf16x8*>(smem + off) = hv;
    }
    __syncthreads();

    const int arow = l & 15;
    const int abyte = (l >> 4) * 16;

    // ---- GEMM1: wave w owns cols [w*32, w*32+32) of H ----
    f32x4 acc[4][2];
    #pragma unroll
    for (int ntl = 0; ntl < 2; ++ntl) {
        float bv = b1[w * 32 + ntl * 16 + (l & 15)];
        #pragma unroll
        for (int mt = 0; mt < 4; ++mt)
            acc[mt][ntl] = (f32x4){bv, bv, bv, bv};
    }
    for (int kt = 0; kt < 8; ++kt) {
        bf16x8 ah[4];
        #pragma unroll
        for (int mt = 0; mt < 4; ++mt) {
            int row = mt * 16 + arow;
            int off = row * 512 + ((kt * 64 + abyte) ^ ((row & 7) << 4));
            ah[mt] = *reinterpret_cast<const bf16x8*>(smem + off);
        }
        #pragma unroll
        for (int ntl = 0; ntl < 2; ++ntl) {
            int nt = w * 2 + ntl;
            size_t boff = ((size_t)(kt * 16 + nt) * 64 + l) * 8;
            bf16x8 bh = *reinterpret_cast<const bf16x8*>(w1h + boff);
            #pragma unroll
            for (int mt = 0; mt < 4; ++mt)
                acc[mt][ntl] = __builtin_amdgcn_mfma_f32_16x16x32_bf16(ah[mt], bh, acc[mt][ntl], 0, 0, 0);
        }
    }
    __syncthreads();  // all X reads done; LDS becomes H

    // ---- relu + write H bf16 (same swizzle) ----
    #pragma unroll
    for (int mt = 0; mt < 4; ++mt)
        #pragma unroll
        for (int ntl = 0; ntl < 2; ++ntl) {
            int col = w * 32 + ntl * 16 + (l & 15);
            #pragma unroll
            for (int r = 0; r < 4; ++r) {
                int row = mt * 16 + (l >> 4) * 4 + r;
                int off = row * 512 + ((col * 2) ^ ((row & 7) << 4));
                *reinterpret_cast<bf16*>(smem + off) = (bf16)fmaxf(acc[mt][ntl][r], 0.f);
            }
        }
    __syncthreads();

    // ---- GEMM2: wave w owns cols [w*16, w*16+16) of out ----
    f32x4 acc2[4];
    {
        float bv = b2[w * 16 + (l & 15)];
        #pragma unroll
        for (int mt = 0; mt < 4; ++mt)
            acc2[mt] = (f32x4){bv, bv, bv, bv};
    }
    for (int kt = 0; kt < 8; ++kt) {
        bf16x8 ah[4];
        #pragma unroll
        for (int mt = 0; mt < 4; ++mt) {
            int row = mt * 16 + arow;
            int off = row * 512 + ((kt * 64 + abyte) ^ ((row & 7) << 4));
            ah[mt] = *reinterpret_cast<const bf16x8*>(smem + off);
        }
        size_t boff = ((size_t)(kt * 8 + w) * 64 + l) * 8;
        bf16x8 bh = *reinterpret_cast<const bf16x8*>(w2h + boff);
        #pragma unroll
        for (int mt = 0; mt < 4; ++mt)
            acc2[mt] = __builtin_amdgcn_mfma_f32_16x16x32_bf16(ah[mt], bh, acc2[mt], 0, 0, 0);
    }
    #pragma unroll
    for (int mt = 0; mt < 4; ++mt) {
        int col = w * 16 + (l & 15);
        #pragma unroll
        for (int r = 0; r < 4; ++r) {
            int row = mt * 16 + (l >> 4) * 4 + r;
            int n = n0 + row;
            if (n < N) out[(size_t)n * DD + col] = acc2[mt][r];
        }
    }
}

// ============================================================================
// fallback path (tiny ws): atomic scatter + fp32 VALU MLP
// ============================================================================
__global__ __launch_bounds__(256) void scatter_k(const float* __restrict__ emb,
        const int* __restrict__ src, const int* __restrict__ dst,
        float* nbr, float* __restrict__ cnt, int E) {
    int e = blockIdx.x * 8 + (threadIdx.x >> 5);
    if (e >= E) return;
    int lane = threadIdx.x & 31;
    int s = src[e];
    int d = dst[e];
    const float4 v = *reinterpret_cast<const float4*>(&emb[(size_t)s * DD + lane * 4]);
    float* o = &nbr[(size_t)d * DD + lane * 4];
    atomicAdd(o + 0, v.x);
    atomicAdd(o + 1, v.y);
    atomicAdd(o + 2, v.z);
    atomicAdd(o + 3, v.w);
    if (lane == 0) atomicAdd(&cnt[d], 1.0f);
}

__global__ __launch_bounds__(256) void mlp_k(const float* __restrict__ emb,
        const float* nbr, const float* cnt,
        const float* __restrict__ W1, const float* __restrict__ b1,
        const float* __restrict__ W2, const float* __restrict__ b2,
        float* out, int N) {
    __shared__ float smem[BM * K1];
    const int t = threadIdx.x;
    const int n0 = blockIdx.x * BM;
    #pragma unroll
    for (int it = 0; it < 16; ++it) {
        int idx = it * 256 + t;
        int r = idx >> 6;
        int c4 = idx & 63;
        int n = n0 + r;
        float4 v = make_float4(0.f, 0.f, 0.f, 0.f);
        if (n < N) {
            if (c4 < 32) {
                v = *reinterpret_cast<const float4*>(&emb[(size_t)n * DD + c4 * 4]);
            } else {
                float c = cnt[n];
                if (c > 0.f) {
                    v = *reinterpret_cast<const float4*>(&nbr[(size_t)n * DD + (c4 - 32) * 4]);
                    float inv = 1.f / c;
                    v.x *= inv; v.y *= inv; v.z *= inv; v.w *= inv;
                } else {
                    v = *reinterpret_cast<const float4*>(&emb[(size_t)n * DD + (c4 - 32) * 4]);
                }
            }
        }
        *reinterpret_cast<float4*>(&smem[idx * 4]) = v;
    }
    __syncthreads();
    const int tx = t & 31;
    const int ty = t >> 5;
    const int r0 = ty * 8;
    {
        const int c0 = tx * 8;
        float acc[8][8];
        const float4 bva = *reinterpret_cast<const float4*>(&b1[c0]);
        const float4 bvb = *reinterpret_cast<const float4*>(&b1[c0 + 4]);
        #pragma unroll
        for (int i = 0; i < 8; ++i) {
            acc[i][0] = bva.x; acc[i][1] = bva.y; acc[i][2] = bva.z; acc[i][3] = bva.w;
            acc[i][4] = bvb.x; acc[i][5] = bvb.y; acc[i][6] = bvb.z; acc[i][7] = bvb.w;
        }
        for (int k0 = 0; k0 < K1; k0 += 4) {
            float xs[8][4];
            #pragma unroll
            for (int i = 0; i < 8; ++i) {
                float4 xv = *reinterpret_cast<const float4*>(&smem[(r0 + i) * K1 + k0]);
                xs[i][0] = xv.x; xs[i][1] = xv.y; xs[i][2] = xv.z; xs[i][3] = xv.w;
            }
            #pragma unroll
            for (int kk = 0; kk < 4; ++kk) {
                const float4 wa = *reinterpret_cast<const float4*>(&W1[(size_t)(k0 + kk) * HH + c0]);
                const float4 wb = *reinterpret_cast<const float4*>(&W1[(size_t)(k0 + kk) * HH + c0 + 4]);
                #pragma unroll
                for (int i = 0; i < 8; ++i) {
                    float x = xs[i][kk];
                    acc[i][0] += x * wa.x; acc[i][1] += x * wa.y;
                    acc[i][2] += x * wa.z; acc[i][3] += x * wa.w;
                    acc[i][4] += x * wb.x; acc[i][5] += x * wb.y;
                    acc[i][6] += x * wb.z; acc[i][7] += x * wb.w;
                }
            }
        }
        __syncthreads();
        #pragma unroll
        for (int i = 0; i < 8; ++i) {
            float4 h0, h1;
            h0.x = fmaxf(acc[i][0], 0.f); h0.y = fmaxf(acc[i][1], 0.f);
            h0.z = fmaxf(acc[i][2], 0.f); h0.w = fmaxf(acc[i][3], 0.f);
            h1.x = fmaxf(acc[i][4], 0.f); h1.y = fmaxf(acc[i][5], 0.f);
            h1.z = fmaxf(acc[i][6], 0.f); h1.w = fmaxf(acc[i][7], 0.f);
            *reinterpret_cast<float4*>(&smem[(r0 + i) * HH + c0]) = h0;
            *reinterpret_cast<float4*>(&smem[(r0 + i) * HH + c0 + 4]) = h1;
        }
        __syncthreads();
    }
    {
        const int c0 = tx * 4;
        float acc[8][4];
        const float4 bv = *reinterpret_cast<const float4*>(&b2[c0]);
        #pragma unroll
        for (int i = 0; i < 8; ++i) {
            acc[i][0] = bv.x; acc[i][1] = bv.y; acc[i][2] = bv.z; acc[i][3] = bv.w;
        }
        for (int k0 = 0; k0 < HH; k0 += 4) {
            float hs[8][4];
            #pragma unroll
            for (int i = 0; i < 8; ++i) {
                float4 hv = *reinterpret_cast<const float4*>(&smem[(r0 + i) * HH + k0]);
                hs[i][0] = hv.x; hs[i][1] = hv.y; hs[i][2] = hv.z; hs[i][3] = hv.w;
            }
            #pragma unroll
            for (int kk = 0; kk < 4; ++kk) {
                const float4 w2 = *reinterpret_cast<const float4*>(&W2[(size_t)(k0 + kk) * DD + c0]);
                #pragma unroll
                for (int i = 0; i < 8; ++i) {
                    float h = hs[i][kk];
                    acc[i][0] += h * w2.x; acc[i][1] += h * w2.y;
                    acc[i][2] += h * w2.z; acc[i][3] += h * w2.w;
                }
            }
        }
        #pragma unroll
        for (int i = 0; i < 8; ++i) {
            int n = n0 + r0 + i;
            if (n < N) {
                float4 o;
                o.x = acc[i][0]; o.y = acc[i][1]; o.z = acc[i][2]; o.w = acc[i][3];
                *reinterpret_cast<float4*>(&out[(size_t)n * DD + c0]) = o;
            }
        }
    }
}

extern "C" void kernel_launch(void* const* d_in, const int* in_sizes, int n_in,
                              void* d_out, int out_size, void* d_ws, size_t ws_size,
                              hipStream_t stream) {
    const float* emb = (const float*)d_in[0];
    const int* esrc  = (const int*)d_in[1];
    const int* edst  = (const int*)d_in[2];
    const float* W1  = (const float*)d_in[3];
    const float* b1  = (const float*)d_in[4];
    const float* W2  = (const float*)d_in[5];
    const float* b2  = (const float*)d_in[6];
    float* out = (float*)d_out;

    const int N = in_sizes[0] / DD;
    const int E = in_sizes[1];
    const int nparts = (N + 1023) / 1024;

    // bucket geometry: B = 2^BSH dsts per bucket, NB buckets (<= 512)
    int BSH = 0;
    while ((((size_t)N + ((size_t)1 << BSH) - 1) >> BSH) > 512) ++BSH;
    const int B = 1 << BSH;
    const int NB = (N + B - 1) >> BSH;

    // ws layout: cnt[N] offs[N] part[128] aux[2048] ssrc[E] | packs | emb8 | nbrh
    // pairs (unsigned, E) aliases emb8 (consumed by sortb before cvt8 writes).
    int* cnt  = (int*)d_ws;
    int* offs = cnt + N;
    int* part = offs + N;
    int* aux  = part + 128;
    int* ssrc = aux + 2048;
    char* wp = (char*)(ssrc + E);
    wp = (char*)(((uintptr_t)wp + 15) & ~(uintptr_t)15);
    bf16* w1h = (bf16*)wp;                     // 65536 elems
    bf16* w2h = w1h + 65536;                   // 32768 elems
    unsigned* emb8 = (unsigned*)(w2h + 32768); // N*DD bytes = N*DD/4 words
    bf16* nbrh = (bf16*)(emb8 + (size_t)N * DD / 4);  // N*DD elems
    unsigned* pairs = emb8;                    // alias: E words in emb8+nbrh region
    int* bcnt  = aux;                          // 512
    int* bbase = aux + 512;                    // 513
    int* bpos  = aux + 1280;                   // 512
    const size_t need_base = (size_t)((char*)(w2h + 32768) - (char*)d_ws);
    const size_t need_full = (size_t)((char*)(nbrh + (size_t)N * DD) - (char*)d_ws);
    const bool pairs_fit = ((size_t)E * 4 <= (size_t)N * DD);  // fits emb8 region alone

    if (ws_size >= need_base && nparts <= 128) {
        const bool fast = (ws_size >= need_full) && pairs_fit && (BSH <= 8) &&
                          (N < (1 << 24)) && ((N & 7) == 0) && (NB <= 512);
        packW_k<<<dim3(192), dim3(64), 0, stream>>>(W1, W2, w1h, w2h);
        if (fast) {
            hipMemsetAsync(bcnt, 0, 512 * sizeof(int), stream);
            countb_k<<<dim3(512), dim3(256), 0, stream>>>(edst, bcnt, E, BSH);
            scanb_k<<<dim3(1), dim3(512), 0, stream>>>(bcnt, bbase, bpos, NB, E);
            part_k<<<dim3((E + CHP - 1) / CHP), dim3(256), 0, stream>>>(
                esrc, edst, bpos, pairs, E, BSH, B - 1);
            sortb_k<<<dim3(NB), dim3(256), 0, stream>>>(pairs, bbase, offs, ssrc, N, BSH);
            // pairs consumed; emb8 region free now
            cvt8_k<<<dim3(2048), dim3(256), 0, stream>>>(emb, emb8, (size_t)N * DD / 8);
            gather8_k<<<dim3((N + 3) / 4), dim3(256), 0, stream>>>(emb8, emb, offs, ssrc, nbrh, N);
            mlp_mfma_k<<<dim3((N + BM - 1) / BM), dim3(512), 0, stream>>>(
                emb, nullptr, nbrh, w1h, b1, w2h, b2, out, N);
        } else {
            hipMemsetAsync(cnt, 0, (size_t)N * sizeof(int), stream);
            hist_k<<<dim3(1024), dim3(256), 0, stream>>>(edst, cnt, E);
            scan1_k<<<dim3(nparts), dim3(256), 0, stream>>>(cnt, offs, part, N);
            scan2_k<<<dim3(1), dim3(128), 0, stream>>>(part, nparts);
            scan3_k<<<dim3(512), dim3(256), 0, stream>>>(offs, part, N);
            const int nchunks = (E + CH - 1) / CH;
            bucket_k<<<dim3(nchunks * 8), dim3(256), 0, stream>>>(esrc, edst, offs, ssrc, E, N);
            gather_k<<<dim3((N + 3) / 4), dim3(256), 0, stream>>>(emb, offs, ssrc, out, N);
            mlp_mfma_k<<<dim3((N + BM - 1) / BM), dim3(512), 0, stream>>>(
                emb, out, nullptr, w1h, b1, w2h, b2, out, N);
        }
    } else {
        float* fcnt = (float*)d_ws;
        hipMemsetAsync(out, 0, (size_t)N * DD * sizeof(float), stream);
        hipMemsetAsync(fcnt, 0, (size_t)N * sizeof(float), stream);
        scatter_k<<<dim3((E + 7) / 8), dim3(256), 0, stream>>>(emb, esrc, edst, out, fcnt, E);
        mlp_k<<<dim3((N + BM - 1) / BM), dim3(256), 0, stream>>>(
            emb, out, fcnt, W1, b1, W2, b2, out, N);
    }
}

// Round 14
// 153.860 us; speedup vs baseline: 1.1532x; 1.1532x over previous
//
#include <hip/hip_runtime.h>

#define DD 128   // embed dim
#define HH 256   // hidden dim
#define K1 256   // 2*DD
#define BM 64    // node tile
#define CH 2048  // edges per chunk in legacy bucket scatter
#define CH1 4096 // edges per chunk in part_k
#define CAP 8192 // max edges per bucket for LDS-staged sort

typedef __bf16 bf16;
typedef __attribute__((ext_vector_type(8))) __bf16 bf16x8;
typedef __attribute__((ext_vector_type(4))) float f32x4;
typedef __attribute__((ext_vector_type(2))) float f32x2;

// ============================================================================
// graph sort: bucket (B=2^BSH<=256 dsts, NB<=512 buckets) 2-pass sort with
// int-packed (dloc<<24|src) pairs. Produces ssrc + offs (inclusive ends).
// ============================================================================

__global__ __launch_bounds__(256) void countb_k(const int* __restrict__ dst,
                                                int* __restrict__ bcnt,
                                                int E, int BSH) {
    __shared__ int c[512];
    for (int j = threadIdx.x; j < 512; j += 256) c[j] = 0;
    __syncthreads();
    for (int e = blockIdx.x * 256 + threadIdx.x; e < E; e += gridDim.x * 256)
        atomicAdd(&c[dst[e] >> BSH], 1);
    __syncthreads();
    for (int j = threadIdx.x; j < 512; j += 256)
        if (c[j]) atomicAdd(&bcnt[j], c[j]);
}

__global__ __launch_bounds__(512) void scanb_k(const int* __restrict__ bcnt,
                                               int* __restrict__ bbase,
                                               int* __restrict__ bpos,
                                               int NB, int E) {
    __shared__ int s[512];
    const int t = threadIdx.x;
    int v = (t < NB) ? bcnt[t] : 0;
    s[t] = v;
    __syncthreads();
    for (int off = 1; off < 512; off <<= 1) {
        int y = (t >= off) ? s[t - off] : 0;
        __syncthreads();
        s[t] += y;
        __syncthreads();
    }
    int excl = s[t] - v;
    if (t < NB) { bbase[t] = excl; bpos[t] = excl; }
    if (t == 0) bbase[NB] = E;
}

// pass 1: scatter packed (dloc<<24 | src) into bucket-contiguous runs
__global__ __launch_bounds__(256) void part_k(const int* __restrict__ src,
                                              const int* __restrict__ dst,
                                              int* __restrict__ bpos,
                                              unsigned* __restrict__ pairs,
                                              int E, int BSH, int Bm1) {
    __shared__ int lcnt[512];
    __shared__ int lbase[512];
    const int t = threadIdx.x;
    const int e0 = blockIdx.x * CH1;
    const int e1 = min(E, e0 + CH1);
    for (int j = t; j < 512; j += 256) lcnt[j] = 0;
    __syncthreads();
    int rs[CH1 / 256];
    #pragma unroll
    for (int k = 0; k < CH1 / 256; ++k) {
        int e = e0 + k * 256 + t;
        int b = -1;
        if (e < e1) { b = dst[e] >> BSH; atomicAdd(&lcnt[b], 1); }
        rs[k] = b;
    }
    __syncthreads();
    for (int j = t; j < 512; j += 256) {
        int c = lcnt[j];
        lbase[j] = c ? atomicAdd(&bpos[j], c) : 0;
        lcnt[j] = 0;
    }
    __syncthreads();
    #pragma unroll
    for (int k = 0; k < CH1 / 256; ++k) {
        int e = e0 + k * 256 + t;
        if (e < e1) {
            int b = rs[k];
            int slot = lbase[b] + atomicAdd(&lcnt[b], 1);
            pairs[slot] = ((unsigned)(dst[e] & Bm1) << 24) | (unsigned)src[e];
        }
    }
}

// pass 2: one block per bucket — per-dst LDS histogram+scan (writes offs),
// LDS-staged counting sort, dense coalesced ssrc write-out.
__global__ __launch_bounds__(256) void sortb_k(const unsigned* __restrict__ pairs,
                                               const int* __restrict__ bbase,
                                               int* __restrict__ offs,
                                               int* __restrict__ ssrc,
                                               int N, int BSH) {
    __shared__ int hist[512];
    __shared__ int pref[512];
    __shared__ int run[512];
    __shared__ int sorted[CAP];
    const int t = threadIdx.x;
    const int b = blockIdx.x;
    const int B = 1 << BSH;
    const int d0 = b << BSH;
    const int nd = min(B, N - d0);
    const int rb = bbase[b], re = bbase[b + 1];
    const int cntE = re - rb;
    for (int j = t; j < 512; j += 256) hist[j] = 0;
    __syncthreads();
    for (int i = rb + t; i < re; i += 256)
        atomicAdd(&hist[pairs[i] >> 24], 1);
    __syncthreads();
    for (int j = t; j < 512; j += 256) pref[j] = hist[j];
    __syncthreads();
    for (int off = 1; off < 512; off <<= 1) {
        int j2 = t + 256;
        int v0 = (t >= off) ? pref[t - off] : 0;
        int v1 = (j2 >= off) ? pref[j2 - off] : 0;
        __syncthreads();
        pref[t] += v0;
        pref[j2] += v1;
        __syncthreads();
    }
    for (int j = t; j < nd; j += 256) offs[d0 + j] = rb + pref[j];
    for (int j = t; j < 512; j += 256) run[j] = pref[j] - hist[j];
    __syncthreads();
    if (cntE <= CAP) {
        for (int i = rb + t; i < re; i += 256) {
            unsigned p = pairs[i];
            int pos = atomicAdd(&run[p >> 24], 1);
            sorted[pos] = (int)(p & 0xFFFFFFu);
        }
        __syncthreads();
        for (int i = t; i < cntE; i += 256) ssrc[rb + i] = sorted[i];
    } else {
        for (int i = rb + t; i < re; i += 256) {
            unsigned p = pairs[i];
            int pos = atomicAdd(&run[p >> 24], 1);
            ssrc[rb + pos] = (int)(p & 0xFFFFFFu);
        }
    }
}

// ============================================================================
// legacy graph kernels (fallback when ws too small / shapes odd)
// ============================================================================

__global__ __launch_bounds__(256) void hist_k(const int* __restrict__ dst,
                                              int* __restrict__ cnt, int E) {
    for (int e = blockIdx.x * blockDim.x + threadIdx.x; e < E;
         e += gridDim.x * blockDim.x)
        atomicAdd(&cnt[dst[e]], 1);
}

__global__ __launch_bounds__(256) void scan1_k(const int* __restrict__ cnt,
                                               int* __restrict__ offs,
                                               int* __restrict__ part, int N) {
    __shared__ int sdata[256];
    const int b = blockIdx.x, t = threadIdx.x;
    const int base = b * 1024 + t * 4;
    int v[4], sum = 0;
    #pragma unroll
    for (int i = 0; i < 4; ++i) {
        int idx = base + i;
        v[i] = (idx < N) ? cnt[idx] : 0;
        sum += v[i];
    }
    sdata[t] = sum;
    __syncthreads();
    for (int off = 1; off < 256; off <<= 1) {
        int y = (t >= off) ? sdata[t - off] : 0;
        __syncthreads();
        sdata[t] += y;
        __syncthreads();
    }
    int excl = sdata[t] - sum;
    if (t == 255) part[b] = sdata[255];
    int run = excl;
    #pragma unroll
    for (int i = 0; i < 4; ++i) {
        int idx = base + i;
        if (idx < N) offs[idx] = run;
        run += v[i];
    }
}

__global__ __launch_bounds__(128) void scan2_k(int* __restrict__ part, int nparts) {
    __shared__ int sdata[128];
    const int t = threadIdx.x;
    int v = (t < nparts) ? part[t] : 0;
    sdata[t] = v;
    __syncthreads();
    for (int off = 1; off < 128; off <<= 1) {
        int y = (t >= off) ? sdata[t - off] : 0;
        __syncthreads();
        sdata[t] += y;
        __syncthreads();
    }
    if (t < nparts) part[t] = sdata[t] - v;
}

__global__ __launch_bounds__(256) void scan3_k(int* __restrict__ offs,
                                               const int* __restrict__ part, int N) {
    for (int i = blockIdx.x * blockDim.x + threadIdx.x; i < N;
         i += gridDim.x * blockDim.x)
        offs[i] += part[i >> 10];
}

__global__ __launch_bounds__(256) void bucket_k(const int* __restrict__ src,
                                                const int* __restrict__ dst,
                                                int* __restrict__ offs,
                                                int* __restrict__ ssrc,
                                                int E, int N) {
    const int r = blockIdx.x & 7;
    const int chunk = blockIdx.x >> 3;
    const int lo = r * (N >> 3);
    const int hi = (r == 7) ? N : lo + (N >> 3);
    const int e0 = chunk * CH;
    const int e1 = min(E, e0 + CH);
    for (int e = e0 + threadIdx.x; e < e1; e += 256) {
        int d = dst[e];
        if (d >= lo && d < hi) {
            int pos = atomicAdd(&offs[d], 1);
            ssrc[pos] = src[e];
        }
    }
}

// fp32-row gather (legacy fallback); writes fp32 nbr
__global__ __launch_bounds__(256) void gather_k(const float* __restrict__ emb,
                                                const int* __restrict__ offs,
                                                const int* __restrict__ ssrc,
                                                float* __restrict__ nbr, int N) {
    const int wid = threadIdx.x >> 6;
    const int lane = threadIdx.x & 63;
    const int d = blockIdx.x * 4 + wid;
    if (d >= N) return;
    const int sub = lane >> 5;
    const int c = (lane & 31) * 4;
    const int start = (d == 0) ? 0 : offs[d - 1];
    const int end = offs[d];
    float4 acc = make_float4(0.f, 0.f, 0.f, 0.f);
    int e = start;
    for (; e + 4 <= end; e += 4) {
        int s0 = ssrc[e + sub];
        int s1 = ssrc[e + 2 + sub];
        float4 v0 = *reinterpret_cast<const float4*>(&emb[(size_t)s0 * DD + c]);
        float4 v1 = *reinterpret_cast<const float4*>(&emb[(size_t)s1 * DD + c]);
        acc.x += v0.x + v1.x; acc.y += v0.y + v1.y;
        acc.z += v0.z + v1.z; acc.w += v0.w + v1.w;
    }
    for (; e + 2 <= end; e += 2) {
        int s = ssrc[e + sub];
        float4 v = *reinterpret_cast<const float4*>(&emb[(size_t)s * DD + c]);
        acc.x += v.x; acc.y += v.y; acc.z += v.z; acc.w += v.w;
    }
    if (e < end && sub == 0) {
        int s = ssrc[e];
        float4 v = *reinterpret_cast<const float4*>(&emb[(size_t)s * DD + c]);
        acc.x += v.x; acc.y += v.y; acc.z += v.z; acc.w += v.w;
    }
    acc.x += __shfl_xor(acc.x, 32);
    acc.y += __shfl_xor(acc.y, 32);
    acc.z += __shfl_xor(acc.z, 32);
    acc.w += __shfl_xor(acc.w, 32);
    if (sub == 0) {
        if (end > start) {
            float inv = 1.f / (float)(end - start);
            acc.x *= inv; acc.y *= inv; acc.z *= inv; acc.w *= inv;
        } else {
            acc = *reinterpret_cast<const float4*>(&emb[(size_t)d * DD + c]);
        }
        *reinterpret_cast<float4*>(&nbr[(size_t)d * DD + c]) = acc;
    }
}

// ============================================================================
// emb fp32 -> fp8 e4m3 copy (gather source; one 128B line per row)
// ============================================================================
__global__ __launch_bounds__(256) void cvt8_k(const float* __restrict__ emb,
                                              unsigned* __restrict__ emb8,
                                              size_t n8) {
    for (size_t i = blockIdx.x * blockDim.x + threadIdx.x; i < n8;
         i += (size_t)gridDim.x * blockDim.x) {
        float4 a = *reinterpret_cast<const float4*>(&emb[i * 8]);
        float4 b = *reinterpret_cast<const float4*>(&emb[i * 8 + 4]);
        int w0 = __builtin_amdgcn_cvt_pk_fp8_f32(a.x, a.y, 0, false);
        w0 = __builtin_amdgcn_cvt_pk_fp8_f32(a.z, a.w, w0, true);
        int w1 = __builtin_amdgcn_cvt_pk_fp8_f32(b.x, b.y, 0, false);
        w1 = __builtin_amdgcn_cvt_pk_fp8_f32(b.z, b.w, w1, true);
        uint2 o; o.x = (unsigned)w0; o.y = (unsigned)w1;
        *reinterpret_cast<uint2*>(&emb8[i * 2]) = o;
    }
}

// accumulate 8 fp8 (uint2) into acc[8]
__device__ __forceinline__ void acc8(float* acc, uint2 v) {
    f32x2 p;
    p = __builtin_amdgcn_cvt_pk_f32_fp8(v.x, false); acc[0] += p[0]; acc[1] += p[1];
    p = __builtin_amdgcn_cvt_pk_f32_fp8(v.x, true);  acc[2] += p[0]; acc[3] += p[1];
    p = __builtin_amdgcn_cvt_pk_f32_fp8(v.y, false); acc[4] += p[0]; acc[5] += p[1];
    p = __builtin_amdgcn_cvt_pk_f32_fp8(v.y, true);  acc[6] += p[0]; acc[7] += p[1];
}

// ============================================================================
// one wave per dst, fp8 rows (128B): 4 edge slots x 16 lanes x 8B, 4 loads in
// flight; HW fp8->f32 cvt; fp32 accumulate; bf16 out row.
// ============================================================================
__global__ __launch_bounds__(256) void gather8_k(const unsigned* __restrict__ emb8,
                                                 const float* __restrict__ emb,
                                                 const int* __restrict__ offs,
                                                 const int* __restrict__ ssrc,
                                                 bf16* __restrict__ nbrh, int N) {
    const int wid = threadIdx.x >> 6;
    const int lane = threadIdx.x & 63;
    const int d = blockIdx.x * 4 + wid;
    if (d >= N) return;
    const int slot = lane >> 4;          // 4 edge slots
    const int c8 = (lane & 15) * 8;      // fp8 column base (0..120)
    const int start = (d == 0) ? 0 : offs[d - 1];
    const int end = offs[d];
    float acc[8];
    #pragma unroll
    for (int j = 0; j < 8; ++j) acc[j] = 0.f;
    int e = start;
    for (; e + 16 <= end; e += 16) {
        int s0 = ssrc[e + slot];
        int s1 = ssrc[e + 4 + slot];
        int s2 = ssrc[e + 8 + slot];
        int s3 = ssrc[e + 12 + slot];
        uint2 v0 = *reinterpret_cast<const uint2*>(&emb8[((size_t)s0 * DD + c8) >> 2]);
        uint2 v1 = *reinterpret_cast<const uint2*>(&emb8[((size_t)s1 * DD + c8) >> 2]);
        uint2 v2 = *reinterpret_cast<const uint2*>(&emb8[((size_t)s2 * DD + c8) >> 2]);
        uint2 v3 = *reinterpret_cast<const uint2*>(&emb8[((size_t)s3 * DD + c8) >> 2]);
        acc8(acc, v0); acc8(acc, v1); acc8(acc, v2); acc8(acc, v3);
    }
    for (; e + 8 <= end; e += 8) {
        int s0 = ssrc[e + slot];
        int s1 = ssrc[e + 4 + slot];
        uint2 v0 = *reinterpret_cast<const uint2*>(&emb8[((size_t)s0 * DD + c8) >> 2]);
        uint2 v1 = *reinterpret_cast<const uint2*>(&emb8[((size_t)s1 * DD + c8) >> 2]);
        acc8(acc, v0); acc8(acc, v1);
    }
    for (; e + 4 <= end; e += 4) {
        int s0 = ssrc[e + slot];
        uint2 v0 = *reinterpret_cast<const uint2*>(&emb8[((size_t)s0 * DD + c8) >> 2]);
        acc8(acc, v0);
    }
    if (slot < end - e) {
        int s0 = ssrc[e + slot];
        uint2 v0 = *reinterpret_cast<const uint2*>(&emb8[((size_t)s0 * DD + c8) >> 2]);
        acc8(acc, v0);
    }
    #pragma unroll
    for (int j = 0; j < 8; ++j) {
        acc[j] += __shfl_xor(acc[j], 16);
        acc[j] += __shfl_xor(acc[j], 32);
    }
    if (slot == 0) {
        bf16x8 o;
        if (end > start) {
            float inv = 1.f / (float)(end - start);
            #pragma unroll
            for (int j = 0; j < 8; ++j) o[j] = (bf16)(acc[j] * inv);
        } else {
            float4 a = *reinterpret_cast<const float4*>(&emb[(size_t)d * DD + c8]);
            float4 b = *reinterpret_cast<const float4*>(&emb[(size_t)d * DD + c8 + 4]);
            o[0]=(bf16)a.x; o[1]=(bf16)a.y; o[2]=(bf16)a.z; o[3]=(bf16)a.w;
            o[4]=(bf16)b.x; o[5]=(bf16)b.y; o[6]=(bf16)b.z; o[7]=(bf16)b.w;
        }
        *reinterpret_cast<bf16x8*>(&nbrh[(size_t)d * DD + c8]) = o;
    }
}

// ============================================================================
// W pre-pack (both weights): fp32 [K x NC] -> bf16 B-fragments.
// ============================================================================
__global__ __launch_bounds__(64) void packW_k(const float* __restrict__ W1,
                                              const float* __restrict__ W2,
                                              bf16* __restrict__ w1h,
                                              bf16* __restrict__ w2h) {
    const int bid = blockIdx.x;
    const float* W; bf16* outp; int NC; int rel;
    if (bid < 128) { W = W1; outp = w1h; NC = HH; rel = bid; }
    else           { W = W2; outp = w2h; NC = DD; rel = bid - 128; }
    const int ntiles = NC >> 4;
    const int kt = rel / ntiles;
    const int nt = rel % ntiles;
    const int l = threadIdx.x;
    const int k0 = kt * 32 + (l >> 4) * 8;
    const int n = nt * 16 + (l & 15);
    bf16x8 hv;
    #pragma unroll
    for (int r = 0; r < 8; ++r)
        hv[r] = (bf16)W[(size_t)(k0 + r) * NC + n];
    *reinterpret_cast<bf16x8*>(outp + ((size_t)rel * 64 + l) * 8) = hv;
}

// ============================================================================
// MFMA MLP, 512 threads (8 waves), single bf16 plane (32 KB LDS).
// ============================================================================
__global__ __launch_bounds__(512) void mlp_mfma_k(const float* __restrict__ emb,
        const float* nbrf, const bf16* __restrict__ nbrh,
        const bf16* __restrict__ w1h, const float* __restrict__ b1,
        const bf16* __restrict__ w2h, const float* __restrict__ b2,
        float* out, int N) {
    __shared__ char smem[BM * K1 * 2];  // 32 KB: [64 rows][256 cols] bf16
    const int t = threadIdx.x;
    const int n0 = blockIdx.x * BM;
    const int l = t & 63;
    const int w = t >> 6;

    // ---- stage X (swizzled: byte_in_row ^= (row&7)<<4) ----
    #pragma unroll
    for (int i = 0; i < 4; ++i) {
        int chunk = i * 512 + t;          // 2048 chunks: 64 rows x 32
        int row = chunk >> 5;
        int c0 = (chunk & 31) * 8;
        int n = n0 + row;
        bf16x8 hv;
        if (n < N) {
            if (c0 >= DD && nbrh != nullptr) {
                hv = *reinterpret_cast<const bf16x8*>(&nbrh[(size_t)n * DD + (c0 - DD)]);
            } else {
                const float* sp = (c0 < DD) ? &emb[(size_t)n * DD + c0]
                                            : &nbrf[(size_t)n * DD + (c0 - DD)];
                float4 a = *reinterpret_cast<const float4*>(sp);
                float4 b = *reinterpret_cast<const float4*>(sp + 4);
                hv[0]=(bf16)a.x; hv[1]=(bf16)a.y; hv[2]=(bf16)a.z; hv[3]=(bf16)a.w;
                hv[4]=(bf16)b.x; hv[5]=(bf16)b.y; hv[6]=(bf16)b.z; hv[7]=(bf16)b.w;
            }
        } else {
            #pragma unroll
            for (int j = 0; j < 8; ++j) hv[j] = (bf16)0.f;
        }
        int off = row * 512 + ((c0 * 2) ^ ((row & 7) << 4));
        *reinterpret_cast<bf16x8*>(smem + off) = hv;
    }
    __syncthreads();

    const int arow = l & 15;
    const int abyte = (l >> 4) * 16;

    // ---- GEMM1: wave w owns cols [w*32, w*32+32) of H ----
    f32x4 acc[4][2];
    #pragma unroll
    for (int ntl = 0; ntl < 2; ++ntl) {
        float bv = b1[w * 32 + ntl * 16 + (l & 15)];
        #pragma unroll
        for (int mt = 0; mt < 4; ++mt)
            acc[mt][ntl] = (f32x4){bv, bv, bv, bv};
    }
    for (int kt = 0; kt < 8; ++kt) {
        bf16x8 ah[4];
        #pragma unroll
        for (int mt = 0; mt < 4; ++mt) {
            int row = mt * 16 + arow;
            int off = row * 512 + ((kt * 64 + abyte) ^ ((row & 7) << 4));
            ah[mt] = *reinterpret_cast<const bf16x8*>(smem + off);
        }
        #pragma unroll
        for (int ntl = 0; ntl < 2; ++ntl) {
            int nt = w * 2 + ntl;
            size_t boff = ((size_t)(kt * 16 + nt) * 64 + l) * 8;
            bf16x8 bh = *reinterpret_cast<const bf16x8*>(w1h + boff);
            #pragma unroll
            for (int mt = 0; mt < 4; ++mt)
                acc[mt][ntl] = __builtin_amdgcn_mfma_f32_16x16x32_bf16(ah[mt], bh, acc[mt][ntl], 0, 0, 0);
        }
    }
    __syncthreads();  // all X reads done; LDS becomes H

    // ---- relu + write H bf16 (same swizzle) ----
    #pragma unroll
    for (int mt = 0; mt < 4; ++mt)
        #pragma unroll
        for (int ntl = 0; ntl < 2; ++ntl) {
            int col = w * 32 + ntl * 16 + (l & 15);
            #pragma unroll
            for (int r = 0; r < 4; ++r) {
                int row = mt * 16 + (l >> 4) * 4 + r;
                int off = row * 512 + ((col * 2) ^ ((row & 7) << 4));
                *reinterpret_cast<bf16*>(smem + off) = (bf16)fmaxf(acc[mt][ntl][r], 0.f);
            }
        }
    __syncthreads();

    // ---- GEMM2: wave w owns cols [w*16, w*16+16) of out ----
    f32x4 acc2[4];
    {
        float bv = b2[w * 16 + (l & 15)];
        #pragma unroll
        for (int mt = 0; mt < 4; ++mt)
            acc2[mt] = (f32x4){bv, bv, bv, bv};
    }
    for (int kt = 0; kt < 8; ++kt) {
        bf16x8 ah[4];
        #pragma unroll
        for (int mt = 0; mt < 4; ++mt) {
            int row = mt * 16 + arow;
            int off = row * 512 + ((kt * 64 + abyte) ^ ((row & 7) << 4));
            ah[mt] = *reinterpret_cast<const bf16x8*>(smem + off);
        }
        size_t boff = ((size_t)(kt * 8 + w) * 64 + l) * 8;
        bf16x8 bh = *reinterpret_cast<const bf16x8*>(w2h + boff);
        #pragma unroll
        for (int mt = 0; mt < 4; ++mt)
            acc2[mt] = __builtin_amdgcn_mfma_f32_16x16x32_bf16(ah[mt], bh, acc2[mt], 0, 0, 0);
    }
    #pragma unroll
    for (int mt = 0; mt < 4; ++mt) {
        int col = w * 16 + (l & 15);
        #pragma unroll
        for (int r = 0; r < 4; ++r) {
            int row = mt * 16 + (l >> 4) * 4 + r;
            int n = n0 + row;
            if (n < N) out[(size_t)n * DD + col] = acc2[mt][r];
        }
    }
}

// ============================================================================
// fallback path (tiny ws): atomic scatter + fp32 VALU MLP
// ============================================================================
__global__ __launch_bounds__(256) void scatter_k(const float* __restrict__ emb,
        const int* __restrict__ src, const int* __restrict__ dst,
        float* nbr, float* __restrict__ cnt, int E) {
    int e = blockIdx.x * 8 + (threadIdx.x >> 5);
    if (e >= E) return;
    int lane = threadIdx.x & 31;
    int s = src[e];
    int d = dst[e];
    const float4 v = *reinterpret_cast<const float4*>(&emb[(size_t)s * DD + lane * 4]);
    float* o = &nbr[(size_t)d * DD + lane * 4];
    atomicAdd(o + 0, v.x);
    atomicAdd(o + 1, v.y);
    atomicAdd(o + 2, v.z);
    atomicAdd(o + 3, v.w);
    if (lane == 0) atomicAdd(&cnt[d], 1.0f);
}

__global__ __launch_bounds__(256) void mlp_k(const float* __restrict__ emb,
        const float* nbr, const float* cnt,
        const float* __restrict__ W1, const float* __restrict__ b1,
        const float* __restrict__ W2, const float* __restrict__ b2,
        float* out, int N) {
    __shared__ float smem[BM * K1];
    const int t = threadIdx.x;
    const int n0 = blockIdx.x * BM;
    #pragma unroll
    for (int it = 0; it < 16; ++it) {
        int idx = it * 256 + t;
        int r = idx >> 6;
        int c4 = idx & 63;
        int n = n0 + r;
        float4 v = make_float4(0.f, 0.f, 0.f, 0.f);
        if (n < N) {
            if (c4 < 32) {
                v = *reinterpret_cast<const float4*>(&emb[(size_t)n * DD + c4 * 4]);
            } else {
                float c = cnt[n];
                if (c > 0.f) {
                    v = *reinterpret_cast<const float4*>(&nbr[(size_t)n * DD + (c4 - 32) * 4]);
                    float inv = 1.f / c;
                    v.x *= inv; v.y *= inv; v.z *= inv; v.w *= inv;
                } else {
                    v = *reinterpret_cast<const float4*>(&emb[(size_t)n * DD + (c4 - 32) * 4]);
                }
            }
        }
        *reinterpret_cast<float4*>(&smem[idx * 4]) = v;
    }
    __syncthreads();
    const int tx = t & 31;
    const int ty = t >> 5;
    const int r0 = ty * 8;
    {
        const int c0 = tx * 8;
        float acc[8][8];
        const float4 bva = *reinterpret_cast<const float4*>(&b1[c0]);
        const float4 bvb = *reinterpret_cast<const float4*>(&b1[c0 + 4]);
        #pragma unroll
        for (int i = 0; i < 8; ++i) {
            acc[i][0] = bva.x; acc[i][1] = bva.y; acc[i][2] = bva.z; acc[i][3] = bva.w;
            acc[i][4] = bvb.x; acc[i][5] = bvb.y; acc[i][6] = bvb.z; acc[i][7] = bvb.w;
        }
        for (int k0 = 0; k0 < K1; k0 += 4) {
            float xs[8][4];
            #pragma unroll
            for (int i = 0; i < 8; ++i) {
                float4 xv = *reinterpret_cast<const float4*>(&smem[(r0 + i) * K1 + k0]);
                xs[i][0] = xv.x; xs[i][1] = xv.y; xs[i][2] = xv.z; xs[i][3] = xv.w;
            }
            #pragma unroll
            for (int kk = 0; kk < 4; ++kk) {
                const float4 wa = *reinterpret_cast<const float4*>(&W1[(size_t)(k0 + kk) * HH + c0]);
                const float4 wb = *reinterpret_cast<const float4*>(&W1[(size_t)(k0 + kk) * HH + c0 + 4]);
                #pragma unroll
                for (int i = 0; i < 8; ++i) {
                    float x = xs[i][kk];
                    acc[i][0] += x * wa.x; acc[i][1] += x * wa.y;
                    acc[i][2] += x * wa.z; acc[i][3] += x * wa.w;
                    acc[i][4] += x * wb.x; acc[i][5] += x * wb.y;
                    acc[i][6] += x * wb.z; acc[i][7] += x * wb.w;
                }
            }
        }
        __syncthreads();
        #pragma unroll
        for (int i = 0; i < 8; ++i) {
            float4 h0, h1;
            h0.x = fmaxf(acc[i][0], 0.f); h0.y = fmaxf(acc[i][1], 0.f);
            h0.z = fmaxf(acc[i][2], 0.f); h0.w = fmaxf(acc[i][3], 0.f);
            h1.x = fmaxf(acc[i][4], 0.f); h1.y = fmaxf(acc[i][5], 0.f);
            h1.z = fmaxf(acc[i][6], 0.f); h1.w = fmaxf(acc[i][7], 0.f);
            *reinterpret_cast<float4*>(&smem[(r0 + i) * HH + c0]) = h0;
            *reinterpret_cast<float4*>(&smem[(r0 + i) * HH + c0 + 4]) = h1;
        }
        __syncthreads();
    }
    {
        const int c0 = tx * 4;
        float acc[8][4];
        const float4 bv = *reinterpret_cast<const float4*>(&b2[c0]);
        #pragma unroll
        for (int i = 0; i < 8; ++i) {
            acc[i][0] = bv.x; acc[i][1] = bv.y; acc[i][2] = bv.z; acc[i][3] = bv.w;
        }
        for (int k0 = 0; k0 < HH; k0 += 4) {
            float hs[8][4];
            #pragma unroll
            for (int i = 0; i < 8; ++i) {
                float4 hv = *reinterpret_cast<const float4*>(&smem[(r0 + i) * HH + k0]);
                hs[i][0] = hv.x; hs[i][1] = hv.y; hs[i][2] = hv.z; hs[i][3] = hv.w;
            }
            #pragma unroll
            for (int kk = 0; kk < 4; ++kk) {
                const float4 w2 = *reinterpret_cast<const float4*>(&W2[(size_t)(k0 + kk) * DD + c0]);
                #pragma unroll
                for (int i = 0; i < 8; ++i) {
                    float h = hs[i][kk];
                    acc[i][0] += h * w2.x; acc[i][1] += h * w2.y;
                    acc[i][2] += h * w2.z; acc[i][3] += h * w2.w;
                }
            }
        }
        #pragma unroll
        for (int i = 0; i < 8; ++i) {
            int n = n0 + r0 + i;
            if (n < N) {
                float4 o;
                o.x = acc[i][0]; o.y = acc[i][1]; o.z = acc[i][2]; o.w = acc[i][3];
                *reinterpret_cast<float4*>(&out[(size_t)n * DD + c0]) = o;
            }
        }
    }
}

extern "C" void kernel_launch(void* const* d_in, const int* in_sizes, int n_in,
                              void* d_out, int out_size, void* d_ws, size_t ws_size,
                              hipStream_t stream) {
    const float* emb = (const float*)d_in[0];
    const int* esrc  = (const int*)d_in[1];
    const int* edst  = (const int*)d_in[2];
    const float* W1  = (const float*)d_in[3];
    const float* b1  = (const float*)d_in[4];
    const float* W2  = (const float*)d_in[5];
    const float* b2  = (const float*)d_in[6];
    float* out = (float*)d_out;

    const int N = in_sizes[0] / DD;
    const int E = in_sizes[1];
    const int nparts = (N + 1023) / 1024;

    // bucket geometry: B = 2^BSH dsts per bucket, NB buckets (<= 512)
    int BSH = 0;
    while ((((size_t)N + ((size_t)1 << BSH) - 1) >> BSH) > 512) ++BSH;
    const int B = 1 << BSH;
    const int NB = (N + B - 1) >> BSH;

    // ws layout: cnt[N] offs[N] part[128] aux[2048] ssrc[E] | packs | emb8 | nbrh
    // pairs (unsigned, E) aliases emb8 (consumed by sortb before cvt8 writes).
    int* cnt  = (int*)d_ws;
    int* offs = cnt + N;
    int* part = offs + N;
    int* aux  = part + 128;
    int* ssrc = aux + 2048;
    char* wp = (char*)(ssrc + E);
    wp = (char*)(((uintptr_t)wp + 15) & ~(uintptr_t)15);
    bf16* w1h = (bf16*)wp;                     // 65536 elems
    bf16* w2h = w1h + 65536;                   // 32768 elems
    unsigned* emb8 = (unsigned*)(w2h + 32768); // N*DD bytes = N*DD/4 words
    bf16* nbrh = (bf16*)(emb8 + (size_t)N * DD / 4);  // N*DD elems
    unsigned* pairs = emb8;                    // alias: E words in emb8+nbrh region
    int* bcnt  = aux;                          // 512
    int* bbase = aux + 512;                    // 513
    int* bpos  = aux + 1280;                   // 512
    const size_t need_base = (size_t)((char*)(w2h + 32768) - (char*)d_ws);
    const size_t need_full = (size_t)((char*)(nbrh + (size_t)N * DD) - (char*)d_ws);
    const bool pairs_fit = ((size_t)E * 4 <= (size_t)N * DD);  // fits emb8 region alone

    if (ws_size >= need_base && nparts <= 128) {
        const bool fast = (ws_size >= need_full) && pairs_fit && (BSH <= 8) &&
                          (N < (1 << 24)) && ((N & 7) == 0) && (NB <= 512);
        packW_k<<<dim3(192), dim3(64), 0, stream>>>(W1, W2, w1h, w2h);
        if (fast) {
            hipMemsetAsync(bcnt, 0, 512 * sizeof(int), stream);
            countb_k<<<dim3(512), dim3(256), 0, stream>>>(edst, bcnt, E, BSH);
            scanb_k<<<dim3(1), dim3(512), 0, stream>>>(bcnt, bbase, bpos, NB, E);
            part_k<<<dim3((E + CH1 - 1) / CH1), dim3(256), 0, stream>>>(
                esrc, edst, bpos, pairs, E, BSH, B - 1);
            sortb_k<<<dim3(NB), dim3(256), 0, stream>>>(pairs, bbase, offs, ssrc, N, BSH);
            // pairs consumed; emb8 region free now
            cvt8_k<<<dim3(2048), dim3(256), 0, stream>>>(emb, emb8, (size_t)N * DD / 8);
            gather8_k<<<dim3((N + 3) / 4), dim3(256), 0, stream>>>(emb8, emb, offs, ssrc, nbrh, N);
            mlp_mfma_k<<<dim3((N + BM - 1) / BM), dim3(512), 0, stream>>>(
                emb, nullptr, nbrh, w1h, b1, w2h, b2, out, N);
        } else {
            hipMemsetAsync(cnt, 0, (size_t)N * sizeof(int), stream);
            hist_k<<<dim3(1024), dim3(256), 0, stream>>>(edst, cnt, E);
            scan1_k<<<dim3(nparts), dim3(256), 0, stream>>>(cnt, offs, part, N);
            scan2_k<<<dim3(1), dim3(128), 0, stream>>>(part, nparts);
            scan3_k<<<dim3(512), dim3(256), 0, stream>>>(offs, part, N);
            const int nchunks = (E + CH - 1) / CH;
            bucket_k<<<dim3(nchunks * 8), dim3(256), 0, stream>>>(esrc, edst, offs, ssrc, E, N);
            gather_k<<<dim3((N + 3) / 4), dim3(256), 0, stream>>>(emb, offs, ssrc, out, N);
            mlp_mfma_k<<<dim3((N + BM - 1) / BM), dim3(512), 0, stream>>>(
                emb, out, nullptr, w1h, b1, w2h, b2, out, N);
        }
    } else {
        float* fcnt = (float*)d_ws;
        hipMemsetAsync(out, 0, (size_t)N * DD * sizeof(float), stream);
        hipMemsetAsync(fcnt, 0, (size_t)N * sizeof(float), stream);
        scatter_k<<<dim3((E + 7) / 8), dim3(256), 0, stream>>>(emb, esrc, edst, out, fcnt, E);
        mlp_k<<<dim3((N + BM - 1) / BM), dim3(256), 0, stream>>>(
            emb, out, fcnt, W1, b1, W2, b2, out, N);
    }
}

// Round 15
// 147.730 us; speedup vs baseline: 1.2011x; 1.0415x over previous
//
#include <hip/hip_runtime.h>

#define DD 128   // embed dim
#define HH 256   // hidden dim
#define K1 256   // 2*DD
#define BM 64    // node tile
#define CH 2048  // edges per chunk in legacy bucket scatter
#define CH1 4096 // edges per chunk in part_k
#define CAP 8192 // max edges per bucket for LDS-staged sort
#define PREP_PACKW 48
#define PREP_COUNT 512
#define PREP_CVT 2048

typedef __bf16 bf16;
typedef __attribute__((ext_vector_type(8))) __bf16 bf16x8;
typedef __attribute__((ext_vector_type(4))) float f32x4;
typedef __attribute__((ext_vector_type(2))) float f32x2;

// ============================================================================
// prep: packW (48 blocks) + bucket count (512 blocks) + emb->fp8 cvt (2048)
// all independent — one launch, concurrent execution.
// ============================================================================
__global__ __launch_bounds__(256) void prep_k(
        const float* __restrict__ W1, const float* __restrict__ W2,
        bf16* __restrict__ w1h, bf16* __restrict__ w2h,
        const int* __restrict__ dst, int* __restrict__ bcnt, int E, int BSH,
        const float* __restrict__ emb, unsigned* __restrict__ emb8, size_t n8) {
    __shared__ int c[512];
    const int bid = blockIdx.x;
    const int t = threadIdx.x;
    if (bid < PREP_PACKW) {
        // ---- packW: 4 fragment-tiles per block ----
        int rel = bid * 4 + (t >> 6);
        const int l = t & 63;
        const float* W; bf16* outp; int NC; int r2;
        if (rel < 128) { W = W1; outp = w1h; NC = HH; r2 = rel; }
        else           { W = W2; outp = w2h; NC = DD; r2 = rel - 128; }
        const int ntiles = NC >> 4;
        const int kt = r2 / ntiles;
        const int nt = r2 % ntiles;
        const int k0 = kt * 32 + (l >> 4) * 8;
        const int n = nt * 16 + (l & 15);
        bf16x8 hv;
        #pragma unroll
        for (int r = 0; r < 8; ++r)
            hv[r] = (bf16)W[(size_t)(k0 + r) * NC + n];
        *reinterpret_cast<bf16x8*>(outp + ((size_t)r2 * 64 + l) * 8) = hv;
    } else if (bid < PREP_PACKW + PREP_COUNT) {
        // ---- bucket histogram ----
        for (int j = t; j < 512; j += 256) c[j] = 0;
        __syncthreads();
        for (int e = (bid - PREP_PACKW) * 256 + t; e < E; e += PREP_COUNT * 256)
            atomicAdd(&c[dst[e] >> BSH], 1);
        __syncthreads();
        for (int j = t; j < 512; j += 256)
            if (c[j]) atomicAdd(&bcnt[j], c[j]);
    } else {
        // ---- emb fp32 -> fp8 e4m3 ----
        for (size_t i = (size_t)(bid - PREP_PACKW - PREP_COUNT) * 256 + t; i < n8;
             i += (size_t)PREP_CVT * 256) {
            float4 a = *reinterpret_cast<const float4*>(&emb[i * 8]);
            float4 b = *reinterpret_cast<const float4*>(&emb[i * 8 + 4]);
            int w0 = __builtin_amdgcn_cvt_pk_fp8_f32(a.x, a.y, 0, false);
            w0 = __builtin_amdgcn_cvt_pk_fp8_f32(a.z, a.w, w0, true);
            int w1 = __builtin_amdgcn_cvt_pk_fp8_f32(b.x, b.y, 0, false);
            w1 = __builtin_amdgcn_cvt_pk_fp8_f32(b.z, b.w, w1, true);
            uint2 o; o.x = (unsigned)w0; o.y = (unsigned)w1;
            *reinterpret_cast<uint2*>(&emb8[i * 2]) = o;
        }
    }
}

__global__ __launch_bounds__(512) void scanb_k(const int* __restrict__ bcnt,
                                               int* __restrict__ bbase,
                                               int* __restrict__ bpos,
                                               int NB, int E) {
    __shared__ int s[512];
    const int t = threadIdx.x;
    int v = (t < NB) ? bcnt[t] : 0;
    s[t] = v;
    __syncthreads();
    for (int off = 1; off < 512; off <<= 1) {
        int y = (t >= off) ? s[t - off] : 0;
        __syncthreads();
        s[t] += y;
        __syncthreads();
    }
    int excl = s[t] - v;
    if (t < NB) { bbase[t] = excl; bpos[t] = excl; }
    if (t == 0) bbase[NB] = E;
}

// pass 1: scatter packed (dloc<<24 | src) into bucket-contiguous runs
__global__ __launch_bounds__(256) void part_k(const int* __restrict__ src,
                                              const int* __restrict__ dst,
                                              int* __restrict__ bpos,
                                              unsigned* __restrict__ pairs,
                                              int E, int BSH, int Bm1) {
    __shared__ int lcnt[512];
    __shared__ int lbase[512];
    const int t = threadIdx.x;
    const int e0 = blockIdx.x * CH1;
    const int e1 = min(E, e0 + CH1);
    for (int j = t; j < 512; j += 256) lcnt[j] = 0;
    __syncthreads();
    int rs[CH1 / 256];
    #pragma unroll
    for (int k = 0; k < CH1 / 256; ++k) {
        int e = e0 + k * 256 + t;
        int b = -1;
        if (e < e1) { b = dst[e] >> BSH; atomicAdd(&lcnt[b], 1); }
        rs[k] = b;
    }
    __syncthreads();
    for (int j = t; j < 512; j += 256) {
        int c = lcnt[j];
        lbase[j] = c ? atomicAdd(&bpos[j], c) : 0;
        lcnt[j] = 0;
    }
    __syncthreads();
    #pragma unroll
    for (int k = 0; k < CH1 / 256; ++k) {
        int e = e0 + k * 256 + t;
        if (e < e1) {
            int b = rs[k];
            int slot = lbase[b] + atomicAdd(&lcnt[b], 1);
            pairs[slot] = ((unsigned)(dst[e] & Bm1) << 24) | (unsigned)src[e];
        }
    }
}

// pass 2: one block per bucket — per-dst LDS histogram+scan (writes offs),
// LDS-staged counting sort, dense coalesced ssrc write-out.
__global__ __launch_bounds__(256) void sortb_k(const unsigned* __restrict__ pairs,
                                               const int* __restrict__ bbase,
                                               int* __restrict__ offs,
                                               int* __restrict__ ssrc,
                                               int N, int BSH) {
    __shared__ int hist[512];
    __shared__ int pref[512];
    __shared__ int run[512];
    __shared__ int sorted[CAP];
    const int t = threadIdx.x;
    const int b = blockIdx.x;
    const int B = 1 << BSH;
    const int d0 = b << BSH;
    const int nd = min(B, N - d0);
    const int rb = bbase[b], re = bbase[b + 1];
    const int cntE = re - rb;
    for (int j = t; j < 512; j += 256) hist[j] = 0;
    __syncthreads();
    for (int i = rb + t; i < re; i += 256)
        atomicAdd(&hist[pairs[i] >> 24], 1);
    __syncthreads();
    for (int j = t; j < 512; j += 256) pref[j] = hist[j];
    __syncthreads();
    for (int off = 1; off < 512; off <<= 1) {
        int j2 = t + 256;
        int v0 = (t >= off) ? pref[t - off] : 0;
        int v1 = (j2 >= off) ? pref[j2 - off] : 0;
        __syncthreads();
        pref[t] += v0;
        pref[j2] += v1;
        __syncthreads();
    }
    for (int j = t; j < nd; j += 256) offs[d0 + j] = rb + pref[j];
    for (int j = t; j < 512; j += 256) run[j] = pref[j] - hist[j];
    __syncthreads();
    if (cntE <= CAP) {
        for (int i = rb + t; i < re; i += 256) {
            unsigned p = pairs[i];
            int pos = atomicAdd(&run[p >> 24], 1);
            sorted[pos] = (int)(p & 0xFFFFFFu);
        }
        __syncthreads();
        for (int i = t; i < cntE; i += 256) ssrc[rb + i] = sorted[i];
    } else {
        for (int i = rb + t; i < re; i += 256) {
            unsigned p = pairs[i];
            int pos = atomicAdd(&run[p >> 24], 1);
            ssrc[rb + pos] = (int)(p & 0xFFFFFFu);
        }
    }
}

// ============================================================================
// legacy graph kernels (fallback when ws too small / shapes odd)
// ============================================================================

__global__ __launch_bounds__(256) void hist_k(const int* __restrict__ dst,
                                              int* __restrict__ cnt, int E) {
    for (int e = blockIdx.x * blockDim.x + threadIdx.x; e < E;
         e += gridDim.x * blockDim.x)
        atomicAdd(&cnt[dst[e]], 1);
}

__global__ __launch_bounds__(256) void scan1_k(const int* __restrict__ cnt,
                                               int* __restrict__ offs,
                                               int* __restrict__ part, int N) {
    __shared__ int sdata[256];
    const int b = blockIdx.x, t = threadIdx.x;
    const int base = b * 1024 + t * 4;
    int v[4], sum = 0;
    #pragma unroll
    for (int i = 0; i < 4; ++i) {
        int idx = base + i;
        v[i] = (idx < N) ? cnt[idx] : 0;
        sum += v[i];
    }
    sdata[t] = sum;
    __syncthreads();
    for (int off = 1; off < 256; off <<= 1) {
        int y = (t >= off) ? sdata[t - off] : 0;
        __syncthreads();
        sdata[t] += y;
        __syncthreads();
    }
    int excl = sdata[t] - sum;
    if (t == 255) part[b] = sdata[255];
    int run = excl;
    #pragma unroll
    for (int i = 0; i < 4; ++i) {
        int idx = base + i;
        if (idx < N) offs[idx] = run;
        run += v[i];
    }
}

__global__ __launch_bounds__(128) void scan2_k(int* __restrict__ part, int nparts) {
    __shared__ int sdata[128];
    const int t = threadIdx.x;
    int v = (t < nparts) ? part[t] : 0;
    sdata[t] = v;
    __syncthreads();
    for (int off = 1; off < 128; off <<= 1) {
        int y = (t >= off) ? sdata[t - off] : 0;
        __syncthreads();
        sdata[t] += y;
        __syncthreads();
    }
    if (t < nparts) part[t] = sdata[t] - v;
}

__global__ __launch_bounds__(256) void scan3_k(int* __restrict__ offs,
                                               const int* __restrict__ part, int N) {
    for (int i = blockIdx.x * blockDim.x + threadIdx.x; i < N;
         i += gridDim.x * blockDim.x)
        offs[i] += part[i >> 10];
}

__global__ __launch_bounds__(256) void bucket_k(const int* __restrict__ src,
                                                const int* __restrict__ dst,
                                                int* __restrict__ offs,
                                                int* __restrict__ ssrc,
                                                int E, int N) {
    const int r = blockIdx.x & 7;
    const int chunk = blockIdx.x >> 3;
    const int lo = r * (N >> 3);
    const int hi = (r == 7) ? N : lo + (N >> 3);
    const int e0 = chunk * CH;
    const int e1 = min(E, e0 + CH);
    for (int e = e0 + threadIdx.x; e < e1; e += 256) {
        int d = dst[e];
        if (d >= lo && d < hi) {
            int pos = atomicAdd(&offs[d], 1);
            ssrc[pos] = src[e];
        }
    }
}

// fp32-row gather (legacy fallback); writes fp32 nbr
__global__ __launch_bounds__(256) void gather_k(const float* __restrict__ emb,
                                                const int* __restrict__ offs,
                                                const int* __restrict__ ssrc,
                                                float* __restrict__ nbr, int N) {
    const int wid = threadIdx.x >> 6;
    const int lane = threadIdx.x & 63;
    const int d = blockIdx.x * 4 + wid;
    if (d >= N) return;
    const int sub = lane >> 5;
    const int c = (lane & 31) * 4;
    const int start = (d == 0) ? 0 : offs[d - 1];
    const int end = offs[d];
    float4 acc = make_float4(0.f, 0.f, 0.f, 0.f);
    int e = start;
    for (; e + 4 <= end; e += 4) {
        int s0 = ssrc[e + sub];
        int s1 = ssrc[e + 2 + sub];
        float4 v0 = *reinterpret_cast<const float4*>(&emb[(size_t)s0 * DD + c]);
        float4 v1 = *reinterpret_cast<const float4*>(&emb[(size_t)s1 * DD + c]);
        acc.x += v0.x + v1.x; acc.y += v0.y + v1.y;
        acc.z += v0.z + v1.z; acc.w += v0.w + v1.w;
    }
    for (; e + 2 <= end; e += 2) {
        int s = ssrc[e + sub];
        float4 v = *reinterpret_cast<const float4*>(&emb[(size_t)s * DD + c]);
        acc.x += v.x; acc.y += v.y; acc.z += v.z; acc.w += v.w;
    }
    if (e < end && sub == 0) {
        int s = ssrc[e];
        float4 v = *reinterpret_cast<const float4*>(&emb[(size_t)s * DD + c]);
        acc.x += v.x; acc.y += v.y; acc.z += v.z; acc.w += v.w;
    }
    acc.x += __shfl_xor(acc.x, 32);
    acc.y += __shfl_xor(acc.y, 32);
    acc.z += __shfl_xor(acc.z, 32);
    acc.w += __shfl_xor(acc.w, 32);
    if (sub == 0) {
        if (end > start) {
            float inv = 1.f / (float)(end - start);
            acc.x *= inv; acc.y *= inv; acc.z *= inv; acc.w *= inv;
        } else {
            acc = *reinterpret_cast<const float4*>(&emb[(size_t)d * DD + c]);
        }
        *reinterpret_cast<float4*>(&nbr[(size_t)d * DD + c]) = acc;
    }
}

// ============================================================================
// W pre-pack standalone (legacy mid path)
// ============================================================================
__global__ __launch_bounds__(64) void packW_k(const float* __restrict__ W1,
                                              const float* __restrict__ W2,
                                              bf16* __restrict__ w1h,
                                              bf16* __restrict__ w2h) {
    const int bid = blockIdx.x;
    const float* W; bf16* outp; int NC; int rel;
    if (bid < 128) { W = W1; outp = w1h; NC = HH; rel = bid; }
    else           { W = W2; outp = w2h; NC = DD; rel = bid - 128; }
    const int ntiles = NC >> 4;
    const int kt = rel / ntiles;
    const int nt = rel % ntiles;
    const int l = threadIdx.x;
    const int k0 = kt * 32 + (l >> 4) * 8;
    const int n = nt * 16 + (l & 15);
    bf16x8 hv;
    #pragma unroll
    for (int r = 0; r < 8; ++r)
        hv[r] = (bf16)W[(size_t)(k0 + r) * NC + n];
    *reinterpret_cast<bf16x8*>(outp + ((size_t)rel * 64 + l) * 8) = hv;
}

// packed accumulate: 8 fp8 (uint2) into 4 x f32x2 (v_pk_add_f32)
__device__ __forceinline__ void acc8p(f32x2* acc, uint2 v) {
    acc[0] += __builtin_amdgcn_cvt_pk_f32_fp8(v.x, false);
    acc[1] += __builtin_amdgcn_cvt_pk_f32_fp8(v.x, true);
    acc[2] += __builtin_amdgcn_cvt_pk_f32_fp8(v.y, false);
    acc[3] += __builtin_amdgcn_cvt_pk_f32_fp8(v.y, true);
}

// ============================================================================
// one wave per dst, fp8 rows (128B): 4 edge slots x 16 lanes x 8B, 4 loads in
// flight; HW fp8->f32 cvt; packed fp32 accumulate; bf16 out row.
// ============================================================================
__global__ __launch_bounds__(256) void gather8_k(const unsigned* __restrict__ emb8,
                                                 const float* __restrict__ emb,
                                                 const int* __restrict__ offs,
                                                 const int* __restrict__ ssrc,
                                                 bf16* __restrict__ nbrh, int N) {
    const int wid = threadIdx.x >> 6;
    const int lane = threadIdx.x & 63;
    const int d = blockIdx.x * 4 + wid;
    if (d >= N) return;
    const int slot = lane >> 4;          // 4 edge slots
    const int c8 = (lane & 15) * 8;      // fp8 column base (0..120)
    const int start = (d == 0) ? 0 : offs[d - 1];
    const int end = offs[d];
    f32x2 acc[4];
    #pragma unroll
    for (int j = 0; j < 4; ++j) acc[j] = (f32x2){0.f, 0.f};
    int e = start;
    for (; e + 16 <= end; e += 16) {
        int s0 = ssrc[e + slot];
        int s1 = ssrc[e + 4 + slot];
        int s2 = ssrc[e + 8 + slot];
        int s3 = ssrc[e + 12 + slot];
        uint2 v0 = *reinterpret_cast<const uint2*>(&emb8[((size_t)s0 * DD + c8) >> 2]);
        uint2 v1 = *reinterpret_cast<const uint2*>(&emb8[((size_t)s1 * DD + c8) >> 2]);
        uint2 v2 = *reinterpret_cast<const uint2*>(&emb8[((size_t)s2 * DD + c8) >> 2]);
        uint2 v3 = *reinterpret_cast<const uint2*>(&emb8[((size_t)s3 * DD + c8) >> 2]);
        acc8p(acc, v0); acc8p(acc, v1); acc8p(acc, v2); acc8p(acc, v3);
    }
    for (; e + 8 <= end; e += 8) {
        int s0 = ssrc[e + slot];
        int s1 = ssrc[e + 4 + slot];
        uint2 v0 = *reinterpret_cast<const uint2*>(&emb8[((size_t)s0 * DD + c8) >> 2]);
        uint2 v1 = *reinterpret_cast<const uint2*>(&emb8[((size_t)s1 * DD + c8) >> 2]);
        acc8p(acc, v0); acc8p(acc, v1);
    }
    for (; e + 4 <= end; e += 4) {
        int s0 = ssrc[e + slot];
        uint2 v0 = *reinterpret_cast<const uint2*>(&emb8[((size_t)s0 * DD + c8) >> 2]);
        acc8p(acc, v0);
    }
    if (slot < end - e) {
        int s0 = ssrc[e + slot];
        uint2 v0 = *reinterpret_cast<const uint2*>(&emb8[((size_t)s0 * DD + c8) >> 2]);
        acc8p(acc, v0);
    }
    #pragma unroll
    for (int j = 0; j < 4; ++j) {
        acc[j][0] += __shfl_xor(acc[j][0], 16);
        acc[j][1] += __shfl_xor(acc[j][1], 16);
        acc[j][0] += __shfl_xor(acc[j][0], 32);
        acc[j][1] += __shfl_xor(acc[j][1], 32);
    }
    if (slot == 0) {
        bf16x8 o;
        if (end > start) {
            float inv = 1.f / (float)(end - start);
            #pragma unroll
            for (int j = 0; j < 4; ++j) {
                o[2 * j]     = (bf16)(acc[j][0] * inv);
                o[2 * j + 1] = (bf16)(acc[j][1] * inv);
            }
        } else {
            float4 a = *reinterpret_cast<const float4*>(&emb[(size_t)d * DD + c8]);
            float4 b = *reinterpret_cast<const float4*>(&emb[(size_t)d * DD + c8 + 4]);
            o[0]=(bf16)a.x; o[1]=(bf16)a.y; o[2]=(bf16)a.z; o[3]=(bf16)a.w;
            o[4]=(bf16)b.x; o[5]=(bf16)b.y; o[6]=(bf16)b.z; o[7]=(bf16)b.w;
        }
        *reinterpret_cast<bf16x8*>(&nbrh[(size_t)d * DD + c8]) = o;
    }
}

// ============================================================================
// MFMA MLP, 512 threads (8 waves), single bf16 plane (32 KB LDS).
// ============================================================================
__global__ __launch_bounds__(512) void mlp_mfma_k(const float* __restrict__ emb,
        const float* nbrf, const bf16* __restrict__ nbrh,
        const bf16* __restrict__ w1h, const float* __restrict__ b1,
        const bf16* __restrict__ w2h, const float* __restrict__ b2,
        float* out, int N) {
    __shared__ char smem[BM * K1 * 2];  // 32 KB: [64 rows][256 cols] bf16
    const int t = threadIdx.x;
    const int n0 = blockIdx.x * BM;
    const int l = t & 63;
    const int w = t >> 6;

    // ---- stage X (swizzled: byte_in_row ^= (row&7)<<4) ----
    #pragma unroll
    for (int i = 0; i < 4; ++i) {
        int chunk = i * 512 + t;          // 2048 chunks: 64 rows x 32
        int row = chunk >> 5;
        int c0 = (chunk & 31) * 8;
        int n = n0 + row;
        bf16x8 hv;
        if (n < N) {
            if (c0 >= DD && nbrh != nullptr) {
                hv = *reinterpret_cast<const bf16x8*>(&nbrh[(size_t)n * DD + (c0 - DD)]);
            } else {
                const float* sp = (c0 < DD) ? &emb[(size_t)n * DD + c0]
                                            : &nbrf[(size_t)n * DD + (c0 - DD)];
                float4 a = *reinterpret_cast<const float4*>(sp);
                float4 b = *reinterpret_cast<const float4*>(sp + 4);
                hv[0]=(bf16)a.x; hv[1]=(bf16)a.y; hv[2]=(bf16)a.z; hv[3]=(bf16)a.w;
                hv[4]=(bf16)b.x; hv[5]=(bf16)b.y; hv[6]=(bf16)b.z; hv[7]=(bf16)b.w;
            }
        } else {
            #pragma unroll
            for (int j = 0; j < 8; ++j) hv[j] = (bf16)0.f;
        }
        int off = row * 512 + ((c0 * 2) ^ ((row & 7) << 4));
        *reinterpret_cast<bf16x8*>(smem + off) = hv;
    }
    __syncthreads();

    const int arow = l & 15;
    const int abyte = (l >> 4) * 16;

    // ---- GEMM1: wave w owns cols [w*32, w*32+32) of H ----
    f32x4 acc[4][2];
    #pragma unroll
    for (int ntl = 0; ntl < 2; ++ntl) {
        float bv = b1[w * 32 + ntl * 16 + (l & 15)];
        #pragma unroll
        for (int mt = 0; mt < 4; ++mt)
            acc[mt][ntl] = (f32x4){bv, bv, bv, bv};
    }
    for (int kt = 0; kt < 8; ++kt) {
        bf16x8 ah[4];
        #pragma unroll
        for (int mt = 0; mt < 4; ++mt) {
            int row = mt * 16 + arow;
            int off = row * 512 + ((kt * 64 + abyte) ^ ((row & 7) << 4));
            ah[mt] = *reinterpret_cast<const bf16x8*>(smem + off);
        }
        #pragma unroll
        for (int ntl = 0; ntl < 2; ++ntl) {
            int nt = w * 2 + ntl;
            size_t boff = ((size_t)(kt * 16 + nt) * 64 + l) * 8;
            bf16x8 bh = *reinterpret_cast<const bf16x8*>(w1h + boff);
            #pragma unroll
            for (int mt = 0; mt < 4; ++mt)
                acc[mt][ntl] = __builtin_amdgcn_mfma_f32_16x16x32_bf16(ah[mt], bh, acc[mt][ntl], 0, 0, 0);
        }
    }
    __syncthreads();  // all X reads done; LDS becomes H

    // ---- relu + write H bf16 (same swizzle) ----
    #pragma unroll
    for (int mt = 0; mt < 4; ++mt)
        #pragma unroll
        for (int ntl = 0; ntl < 2; ++ntl) {
            int col = w * 32 + ntl * 16 + (l & 15);
            #pragma unroll
            for (int r = 0; r < 4; ++r) {
                int row = mt * 16 + (l >> 4) * 4 + r;
                int off = row * 512 + ((col * 2) ^ ((row & 7) << 4));
                *reinterpret_cast<bf16*>(smem + off) = (bf16)fmaxf(acc[mt][ntl][r], 0.f);
            }
        }
    __syncthreads();

    // ---- GEMM2: wave w owns cols [w*16, w*16+16) of out ----
    f32x4 acc2[4];
    {
        float bv = b2[w * 16 + (l & 15)];
        #pragma unroll
        for (int mt = 0; mt < 4; ++mt)
            acc2[mt] = (f32x4){bv, bv, bv, bv};
    }
    for (int kt = 0; kt < 8; ++kt) {
        bf16x8 ah[4];
        #pragma unroll
        for (int mt = 0; mt < 4; ++mt) {
            int row = mt * 16 + arow;
            int off = row * 512 + ((kt * 64 + abyte) ^ ((row & 7) << 4));
            ah[mt] = *reinterpret_cast<const bf16x8*>(smem + off);
        }
        size_t boff = ((size_t)(kt * 8 + w) * 64 + l) * 8;
        bf16x8 bh = *reinterpret_cast<const bf16x8*>(w2h + boff);
        #pragma unroll
        for (int mt = 0; mt < 4; ++mt)
            acc2[mt] = __builtin_amdgcn_mfma_f32_16x16x32_bf16(ah[mt], bh, acc2[mt], 0, 0, 0);
    }
    #pragma unroll
    for (int mt = 0; mt < 4; ++mt) {
        int col = w * 16 + (l & 15);
        #pragma unroll
        for (int r = 0; r < 4; ++r) {
            int row = mt * 16 + (l >> 4) * 4 + r;
            int n = n0 + row;
            if (n < N) out[(size_t)n * DD + col] = acc2[mt][r];
        }
    }
}

// ============================================================================
// fallback path (tiny ws): atomic scatter + fp32 VALU MLP
// ============================================================================
__global__ __launch_bounds__(256) void scatter_k(const float* __restrict__ emb,
        const int* __restrict__ src, const int* __restrict__ dst,
        float* nbr, float* __restrict__ cnt, int E) {
    int e = blockIdx.x * 8 + (threadIdx.x >> 5);
    if (e >= E) return;
    int lane = threadIdx.x & 31;
    int s = src[e];
    int d = dst[e];
    const float4 v = *reinterpret_cast<const float4*>(&emb[(size_t)s * DD + lane * 4]);
    float* o = &nbr[(size_t)d * DD + lane * 4];
    atomicAdd(o + 0, v.x);
    atomicAdd(o + 1, v.y);
    atomicAdd(o + 2, v.z);
    atomicAdd(o + 3, v.w);
    if (lane == 0) atomicAdd(&cnt[d], 1.0f);
}

__global__ __launch_bounds__(256) void mlp_k(const float* __restrict__ emb,
        const float* nbr, const float* cnt,
        const float* __restrict__ W1, const float* __restrict__ b1,
        const float* __restrict__ W2, const float* __restrict__ b2,
        float* out, int N) {
    __shared__ float smem[BM * K1];
    const int t = threadIdx.x;
    const int n0 = blockIdx.x * BM;
    #pragma unroll
    for (int it = 0; it < 16; ++it) {
        int idx = it * 256 + t;
        int r = idx >> 6;
        int c4 = idx & 63;
        int n = n0 + r;
        float4 v = make_float4(0.f, 0.f, 0.f, 0.f);
        if (n < N) {
            if (c4 < 32) {
                v = *reinterpret_cast<const float4*>(&emb[(size_t)n * DD + c4 * 4]);
            } else {
                float c = cnt[n];
                if (c > 0.f) {
                    v = *reinterpret_cast<const float4*>(&nbr[(size_t)n * DD + (c4 - 32) * 4]);
                    float inv = 1.f / c;
                    v.x *= inv; v.y *= inv; v.z *= inv; v.w *= inv;
                } else {
                    v = *reinterpret_cast<const float4*>(&emb[(size_t)n * DD + (c4 - 32) * 4]);
                }
            }
        }
        *reinterpret_cast<float4*>(&smem[idx * 4]) = v;
    }
    __syncthreads();
    const int tx = t & 31;
    const int ty = t >> 5;
    const int r0 = ty * 8;
    {
        const int c0 = tx * 8;
        float acc[8][8];
        const float4 bva = *reinterpret_cast<const float4*>(&b1[c0]);
        const float4 bvb = *reinterpret_cast<const float4*>(&b1[c0 + 4]);
        #pragma unroll
        for (int i = 0; i < 8; ++i) {
            acc[i][0] = bva.x; acc[i][1] = bva.y; acc[i][2] = bva.z; acc[i][3] = bva.w;
            acc[i][4] = bvb.x; acc[i][5] = bvb.y; acc[i][6] = bvb.z; acc[i][7] = bvb.w;
        }
        for (int k0 = 0; k0 < K1; k0 += 4) {
            float xs[8][4];
            #pragma unroll
            for (int i = 0; i < 8; ++i) {
                float4 xv = *reinterpret_cast<const float4*>(&smem[(r0 + i) * K1 + k0]);
                xs[i][0] = xv.x; xs[i][1] = xv.y; xs[i][2] = xv.z; xs[i][3] = xv.w;
            }
            #pragma unroll
            for (int kk = 0; kk < 4; ++kk) {
                const float4 wa = *reinterpret_cast<const float4*>(&W1[(size_t)(k0 + kk) * HH + c0]);
                const float4 wb = *reinterpret_cast<const float4*>(&W1[(size_t)(k0 + kk) * HH + c0 + 4]);
                #pragma unroll
                for (int i = 0; i < 8; ++i) {
                    float x = xs[i][kk];
                    acc[i][0] += x * wa.x; acc[i][1] += x * wa.y;
                    acc[i][2] += x * wa.z; acc[i][3] += x * wa.w;
                    acc[i][4] += x * wb.x; acc[i][5] += x * wb.y;
                    acc[i][6] += x * wb.z; acc[i][7] += x * wb.w;
                }
            }
        }
        __syncthreads();
        #pragma unroll
        for (int i = 0; i < 8; ++i) {
            float4 h0, h1;
            h0.x = fmaxf(acc[i][0], 0.f); h0.y = fmaxf(acc[i][1], 0.f);
            h0.z = fmaxf(acc[i][2], 0.f); h0.w = fmaxf(acc[i][3], 0.f);
            h1.x = fmaxf(acc[i][4], 0.f); h1.y = fmaxf(acc[i][5], 0.f);
            h1.z = fmaxf(acc[i][6], 0.f); h1.w = fmaxf(acc[i][7], 0.f);
            *reinterpret_cast<float4*>(&smem[(r0 + i) * HH + c0]) = h0;
            *reinterpret_cast<float4*>(&smem[(r0 + i) * HH + c0 + 4]) = h1;
        }
        __syncthreads();
    }
    {
        const int c0 = tx * 4;
        float acc[8][4];
        const float4 bv = *reinterpret_cast<const float4*>(&b2[c0]);
        #pragma unroll
        for (int i = 0; i < 8; ++i) {
            acc[i][0] = bv.x; acc[i][1] = bv.y; acc[i][2] = bv.z; acc[i][3] = bv.w;
        }
        for (int k0 = 0; k0 < HH; k0 += 4) {
            float hs[8][4];
            #pragma unroll
            for (int i = 0; i < 8; ++i) {
                float4 hv = *reinterpret_cast<const float4*>(&smem[(r0 + i) * HH + k0]);
                hs[i][0] = hv.x; hs[i][1] = hv.y; hs[i][2] = hv.z; hs[i][3] = hv.w;
            }
            #pragma unroll
            for (int kk = 0; kk < 4; ++kk) {
                const float4 w2 = *reinterpret_cast<const float4*>(&W2[(size_t)(k0 + kk) * DD + c0]);
                #pragma unroll
                for (int i = 0; i < 8; ++i) {
                    float h = hs[i][kk];
                    acc[i][0] += h * w2.x; acc[i][1] += h * w2.y;
                    acc[i][2] += h * w2.z; acc[i][3] += h * w2.w;
                }
            }
        }
        #pragma unroll
        for (int i = 0; i < 8; ++i) {
            int n = n0 + r0 + i;
            if (n < N) {
                float4 o;
                o.x = acc[i][0]; o.y = acc[i][1]; o.z = acc[i][2]; o.w = acc[i][3];
                *reinterpret_cast<float4*>(&out[(size_t)n * DD + c0]) = o;
            }
        }
    }
}

extern "C" void kernel_launch(void* const* d_in, const int* in_sizes, int n_in,
                              void* d_out, int out_size, void* d_ws, size_t ws_size,
                              hipStream_t stream) {
    const float* emb = (const float*)d_in[0];
    const int* esrc  = (const int*)d_in[1];
    const int* edst  = (const int*)d_in[2];
    const float* W1  = (const float*)d_in[3];
    const float* b1  = (const float*)d_in[4];
    const float* W2  = (const float*)d_in[5];
    const float* b2  = (const float*)d_in[6];
    float* out = (float*)d_out;

    const int N = in_sizes[0] / DD;
    const int E = in_sizes[1];
    const int nparts = (N + 1023) / 1024;

    // bucket geometry: B = 2^BSH dsts per bucket, NB buckets (<= 512)
    int BSH = 0;
    while ((((size_t)N + ((size_t)1 << BSH) - 1) >> BSH) > 512) ++BSH;
    const int B = 1 << BSH;
    const int NB = (N + B - 1) >> BSH;

    // ws layout: cnt[N] offs[N] part[128] aux[2048] ssrc[E] | packs | emb8 | nbrh
    // pairs (unsigned, E) aliases NBRH (written by part after prep's cvt, read
    // by sortb, then overwritten by gather8's nbrh output).
    int* cnt  = (int*)d_ws;
    int* offs = cnt + N;
    int* part = offs + N;
    int* aux  = part + 128;
    int* ssrc = aux + 2048;
    char* wp = (char*)(ssrc + E);
    wp = (char*)(((uintptr_t)wp + 15) & ~(uintptr_t)15);
    bf16* w1h = (bf16*)wp;                     // 65536 elems
    bf16* w2h = w1h + 65536;                   // 32768 elems
    unsigned* emb8 = (unsigned*)(w2h + 32768); // N*DD bytes = N*DD/4 words
    bf16* nbrh = (bf16*)(emb8 + (size_t)N * DD / 4);  // N*DD elems
    unsigned* pairs = (unsigned*)nbrh;         // alias: E words in nbrh region
    int* bcnt  = aux;                          // 512
    int* bbase = aux + 512;                    // 513
    int* bpos  = aux + 1280;                   // 512
    const size_t need_base = (size_t)((char*)(w2h + 32768) - (char*)d_ws);
    const size_t need_full = (size_t)((char*)(nbrh + (size_t)N * DD) - (char*)d_ws);
    const bool pairs_fit = ((size_t)E * 4 <= (size_t)N * DD * 2);  // fits nbrh region

    if (ws_size >= need_base && nparts <= 128) {
        const bool fast = (ws_size >= need_full) && pairs_fit && (BSH <= 8) &&
                          (N < (1 << 24)) && ((N & 7) == 0) && (NB <= 512);
        if (fast) {
            hipMemsetAsync(bcnt, 0, 512 * sizeof(int), stream);
            prep_k<<<dim3(PREP_PACKW + PREP_COUNT + PREP_CVT), dim3(256), 0, stream>>>(
                W1, W2, w1h, w2h, edst, bcnt, E, BSH, emb, emb8, (size_t)N * DD / 8);
            scanb_k<<<dim3(1), dim3(512), 0, stream>>>(bcnt, bbase, bpos, NB, E);
            part_k<<<dim3((E + CH1 - 1) / CH1), dim3(256), 0, stream>>>(
                esrc, edst, bpos, pairs, E, BSH, B - 1);
            sortb_k<<<dim3(NB), dim3(256), 0, stream>>>(pairs, bbase, offs, ssrc, N, BSH);
            // pairs consumed; nbrh region free now
            gather8_k<<<dim3((N + 3) / 4), dim3(256), 0, stream>>>(emb8, emb, offs, ssrc, nbrh, N);
            mlp_mfma_k<<<dim3((N + BM - 1) / BM), dim3(512), 0, stream>>>(
                emb, nullptr, nbrh, w1h, b1, w2h, b2, out, N);
        } else {
            packW_k<<<dim3(192), dim3(64), 0, stream>>>(W1, W2, w1h, w2h);
            hipMemsetAsync(cnt, 0, (size_t)N * sizeof(int), stream);
            hist_k<<<dim3(1024), dim3(256), 0, stream>>>(edst, cnt, E);
            scan1_k<<<dim3(nparts), dim3(256), 0, stream>>>(cnt, offs, part, N);
            scan2_k<<<dim3(1), dim3(128), 0, stream>>>(part, nparts);
            scan3_k<<<dim3(512), dim3(256), 0, stream>>>(offs, part, N);
            const int nchunks = (E + CH - 1) / CH;
            bucket_k<<<dim3(nchunks * 8), dim3(256), 0, stream>>>(esrc, edst, offs, ssrc, E, N);
            gather_k<<<dim3((N + 3) / 4), dim3(256), 0, stream>>>(emb, offs, ssrc, out, N);
            mlp_mfma_k<<<dim3((N + BM - 1) / BM), dim3(512), 0, stream>>>(
                emb, out, nullptr, w1h, b1, w2h, b2, out, N);
        }
    } else {
        float* fcnt = (float*)d_ws;
        hipMemsetAsync(out, 0, (size_t)N * DD * sizeof(float), stream);
        hipMemsetAsync(fcnt, 0, (size_t)N * sizeof(float), stream);
        scatter_k<<<dim3((E + 7) / 8), dim3(256), 0, stream>>>(emb, esrc, edst, out, fcnt, E);
        mlp_k<<<dim3((N + BM - 1) / BM), dim3(256), 0, stream>>>(
            emb, out, fcnt, W1, b1, W2, b2, out, N);
    }
}